// Round 1
// baseline (976.489 us; speedup 1.0000x reference)
//
#include <hip/hip_runtime.h>
#include <hip/hip_bf16.h>
#include <math.h>

#define N_NODES 50000
#define N_EDGES 1600000
#define D_IN    32
#define HID     64
#define HEADS   4
#define D_OUT   32
#define NEG_SLOPE 0.2f

// ---------------------------------------------------------------- CSR build
__global__ __launch_bounds__(256) void init_cnt(int* __restrict__ cnt) {
    int i = blockIdx.x * 256 + threadIdx.x;
    if (i < N_NODES) cnt[i] = 1;          // self-loop
}

__global__ __launch_bounds__(256) void count_k(const int* __restrict__ edge,
                                               int* __restrict__ cnt) {
    int i = blockIdx.x * 256 + threadIdx.x;
    if (i < N_EDGES) atomicAdd(&cnt[edge[N_EDGES + i]], 1);
}

// single-block exclusive scan over cnt -> rowptr/cursor; also dinv = rsqrt(deg)
__global__ __launch_bounds__(1024) void scan_k(const int* __restrict__ cnt,
                                               int* __restrict__ rowptr,
                                               int* __restrict__ cursor,
                                               float* __restrict__ dinv) {
    __shared__ int wsum[16];
    __shared__ int carry;
    int t = threadIdx.x, lane = t & 63, wv = t >> 6;
    if (t == 0) carry = 0;
    __syncthreads();
    for (int base = 0; base < N_NODES; base += 1024) {
        int i = base + t;
        int v = (i < N_NODES) ? cnt[i] : 0;
        int inc = v;
#pragma unroll
        for (int d = 1; d < 64; d <<= 1) {
            int u = __shfl_up(inc, d);
            if (lane >= d) inc += u;
        }
        if (lane == 63) wsum[wv] = inc;
        __syncthreads();
        int wo = 0, total = 0;
#pragma unroll
        for (int jj = 0; jj < 16; jj++) {
            int s = wsum[jj];
            if (jj < wv) wo += s;
            total += s;
        }
        int exc = carry + wo + inc - v;
        if (i < N_NODES) {
            rowptr[i] = exc;
            cursor[i] = exc;
            dinv[i]   = rsqrtf((float)v);
        }
        __syncthreads();
        if (t == 0) carry += total;
        __syncthreads();
    }
    if (threadIdx.x == 0) rowptr[N_NODES] = carry;   // == N_EDGES + N_NODES
}

__global__ __launch_bounds__(256) void fill_k(const int* __restrict__ edge,
                                              int* __restrict__ cursor,
                                              int* __restrict__ colidx) {
    int i = blockIdx.x * 256 + threadIdx.x;
    if (i < N_EDGES) {
        int s = edge[i], d = edge[N_EDGES + i];
        int p = atomicAdd(&cursor[d], 1);
        colidx[p] = s;
    } else if (i < N_EDGES + N_NODES) {
        int n = i - N_EDGES;
        int p = atomicAdd(&cursor[n], 1);
        colidx[p] = n;                    // self-loop
    }
}

// ---------------------------------------------------------------- GEMM1: h = x @ W_gcn   (50000x32 @ 32x64)
__global__ __launch_bounds__(256) void gemm1(const float* __restrict__ x,
                                             const float* __restrict__ W,
                                             float* __restrict__ h) {
    __shared__ float Wl[D_IN * HID];      // 8 KB
    int t = threadIdx.x;
    for (int i = t; i < D_IN * HID; i += 256) Wl[i] = W[i];
    __syncthreads();
    int c = t & 63;
    int r = blockIdx.x * 4 + (t >> 6);
    if (r >= N_NODES) return;
    const float4* xr4 = (const float4*)(x + r * D_IN);
    float acc = 0.f;
#pragma unroll
    for (int k4 = 0; k4 < D_IN / 4; k4++) {
        float4 xv = xr4[k4];
        int k = k4 * 4;
        acc += xv.x * Wl[(k+0)*HID + c] + xv.y * Wl[(k+1)*HID + c]
             + xv.z * Wl[(k+2)*HID + c] + xv.w * Wl[(k+3)*HID + c];
    }
    h[r * HID + c] = acc;                 // bias added after aggregation
}

// ---------------------------------------------------------------- GCN aggregate -> h1 (relu)
__global__ __launch_bounds__(256) void gcn_agg(const float* __restrict__ h,
                                               const int* __restrict__ rowptr,
                                               const int* __restrict__ colidx,
                                               const float* __restrict__ dinv,
                                               const float* __restrict__ b,
                                               float* __restrict__ h1) {
    int lane = threadIdx.x & 63;
    int n = blockIdx.x * 4 + (threadIdx.x >> 6);
    if (n >= N_NODES) return;
    int rp = rowptr[n], re = rowptr[n + 1];
    float acc = 0.f;
    for (int e = rp; e < re; e++) {
        int s = colidx[e];                        // wave-uniform broadcast
        acc += dinv[s] * h[s * HID + lane];       // coalesced 256B
    }
    float v = acc * dinv[n] + b[lane];
    h1[n * HID + lane] = fmaxf(v, 0.f);
}

// ---------------------------------------------------------------- GEMM2: hg = h1 @ W_gat  + fused attention dots
// wave = 8 rows; lane holds h1[row][lane]; readlane broadcasts k-th element.
// W in LDS permuted: Wp[k*256 + lane*4 + j] = W[k*256 + j*64 + lane]  (j = head)
__global__ __launch_bounds__(256) void gemm2_att(const float* __restrict__ h1,
                                                 const float* __restrict__ W,
                                                 const float* __restrict__ att_s,
                                                 const float* __restrict__ att_d,
                                                 float* __restrict__ hg,
                                                 float* __restrict__ as_o,
                                                 float* __restrict__ ad_o) {
    __shared__ float Wp[HID * 256];       // 64 KB
    int t = threadIdx.x, lane = t & 63, wv = t >> 6;
    for (int i = t; i < HID * 256; i += 256) {
        int k = i >> 8, rem = i & 255;
        int j = rem >> 6, l = rem & 63;
        Wp[k * 256 + l * 4 + j] = W[i];
    }
    __syncthreads();
    int r0 = blockIdx.x * 32 + wv * 8;
    float hreg[8];
#pragma unroll
    for (int r = 0; r < 8; r++)
        hreg[r] = (r0 + r < N_NODES) ? h1[(r0 + r) * HID + lane] : 0.f;
    float acc[8][4];
#pragma unroll
    for (int r = 0; r < 8; r++)
#pragma unroll
        for (int j = 0; j < 4; j++) acc[r][j] = 0.f;

#pragma unroll 16
    for (int k = 0; k < HID; k++) {
        float4 w4 = *(const float4*)&Wp[k * 256 + lane * 4];   // b128, conflict-free
#pragma unroll
        for (int r = 0; r < 8; r++) {
            float s = __int_as_float(__builtin_amdgcn_readlane(__float_as_int(hreg[r]), k));
            acc[r][0] += s * w4.x;
            acc[r][1] += s * w4.y;
            acc[r][2] += s * w4.z;
            acc[r][3] += s * w4.w;
        }
    }
    // store hg
#pragma unroll
    for (int r = 0; r < 8; r++) {
        if (r0 + r < N_NODES) {
#pragma unroll
            for (int j = 0; j < 4; j++)
                hg[(r0 + r) * 256 + j * 64 + lane] = acc[r][j];
        }
    }
    // fused attention dots: a_s[n][j] = sum_c hg[n][j][c]*att_src[j][c]
    float attS[4], attD[4];
#pragma unroll
    for (int j = 0; j < 4; j++) { attS[j] = att_s[j * 64 + lane]; attD[j] = att_d[j * 64 + lane]; }
#pragma unroll
    for (int r = 0; r < 8; r++) {
#pragma unroll
        for (int j = 0; j < 4; j++) {
            float vs = acc[r][j] * attS[j];
            float vd = acc[r][j] * attD[j];
#pragma unroll
            for (int off = 32; off > 0; off >>= 1) {
                vs += __shfl_xor(vs, off);
                vd += __shfl_xor(vd, off);
            }
            if (lane == 0 && r0 + r < N_NODES) {
                as_o[(r0 + r) * 4 + j] = vs;
                ad_o[(r0 + r) * 4 + j] = vd;
            }
        }
    }
}

// ---------------------------------------------------------------- GAT aggregate (softmax over incoming edges) -> h2 (relu)
__global__ __launch_bounds__(256) void gat_agg(const float* __restrict__ hg,
                                               const int* __restrict__ rowptr,
                                               const int* __restrict__ colidx,
                                               const float* __restrict__ a_s,
                                               const float* __restrict__ a_d,
                                               const float* __restrict__ b,
                                               float* __restrict__ h2) {
    int lane = threadIdx.x & 63;
    int hd = threadIdx.x >> 6;            // wave = head
    int n = blockIdx.x;
    int rp = rowptr[n], re = rowptr[n + 1];
    float ad = a_d[n * 4 + hd];
    // pass 1: segment max (lanes stride edges)
    float m = -1e30f;
    for (int e = rp + lane; e < re; e += 64) {
        int s = colidx[e];
        float v = a_s[s * 4 + hd] + ad;
        v = (v > 0.f) ? v : NEG_SLOPE * v;
        m = fmaxf(m, v);
    }
#pragma unroll
    for (int off = 32; off > 0; off >>= 1) m = fmaxf(m, __shfl_xor(m, off));
    // pass 2: weighted sum
    float den = 0.f, acc = 0.f;
    for (int e = rp; e < re; e++) {
        int s = colidx[e];                               // wave-uniform
        float v = a_s[s * 4 + hd] + ad;
        v = (v > 0.f) ? v : NEG_SLOPE * v;
        float w = __expf(v - m);
        den += w;
        acc += w * hg[s * 256 + hd * 64 + lane];         // coalesced 256B
    }
    float o = acc / den + b[hd * 64 + lane];
    h2[n * 256 + hd * 64 + lane] = fmaxf(o, 0.f);
}

// ---------------------------------------------------------------- GEMM3: out = h2 @ W_fc + b_fc  (50000x256 @ 256x32)
__global__ __launch_bounds__(256) void gemm3(const float* __restrict__ h2,
                                             const float* __restrict__ W,
                                             const float* __restrict__ b,
                                             float* __restrict__ out) {
    __shared__ float Wl[256 * D_OUT];     // 32 KB
    int t = threadIdx.x;
    for (int i = t; i < 256 * D_OUT; i += 256) Wl[i] = W[i];
    __syncthreads();
    int c = t & 31;
    int r = blockIdx.x * 8 + (t >> 5);
    if (r >= N_NODES) return;
    const float4* hr4 = (const float4*)(h2 + r * 256);
    float acc = b[c];
#pragma unroll 8
    for (int k4 = 0; k4 < 64; k4++) {
        float4 hv = hr4[k4];              // wave-broadcast (few distinct rows)
        int k = k4 * 4;
        acc += hv.x * Wl[(k+0)*D_OUT + c] + hv.y * Wl[(k+1)*D_OUT + c]
             + hv.z * Wl[(k+2)*D_OUT + c] + hv.w * Wl[(k+3)*D_OUT + c];
    }
    out[r * D_OUT + c] = acc;
}

// ---------------------------------------------------------------- launch
extern "C" void kernel_launch(void* const* d_in, const int* in_sizes, int n_in,
                              void* d_out, int out_size, void* d_ws, size_t ws_size,
                              hipStream_t stream) {
    const float* x      = (const float*)d_in[0];
    const int*   edge   = (const int*)  d_in[1];
    const float* W_gcn  = (const float*)d_in[2];
    const float* b_gcn  = (const float*)d_in[3];
    const float* W_gat  = (const float*)d_in[4];
    const float* att_s  = (const float*)d_in[5];
    const float* att_d  = (const float*)d_in[6];
    const float* b_gat  = (const float*)d_in[7];
    const float* W_fc   = (const float*)d_in[8];
    const float* b_fc   = (const float*)d_in[9];
    float* out = (float*)d_out;

    char* p = (char*)d_ws;
    auto alloc = [&](size_t bytes) {
        char* q = p;
        p += (bytes + 255) & ~(size_t)255;
        return q;
    };
    float* h      = (float*)alloc((size_t)N_NODES * HID * 4);
    float* h1     = (float*)alloc((size_t)N_NODES * HID * 4);
    float* hg     = (float*)alloc((size_t)N_NODES * 256 * 4);
    float* h2     = (float*)alloc((size_t)N_NODES * 256 * 4);
    float* as_a   = (float*)alloc((size_t)N_NODES * 4 * 4);
    float* ad_a   = (float*)alloc((size_t)N_NODES * 4 * 4);
    float* dinv   = (float*)alloc((size_t)N_NODES * 4);
    int*   cnt    = (int*)  alloc((size_t)N_NODES * 4);
    int*   rowptr = (int*)  alloc((size_t)(N_NODES + 1) * 4);
    int*   cursor = (int*)  alloc((size_t)N_NODES * 4);
    int*   colidx = (int*)  alloc((size_t)(N_EDGES + N_NODES) * 4);

    // CSR build
    init_cnt<<<(N_NODES + 255) / 256, 256, 0, stream>>>(cnt);
    count_k <<<(N_EDGES + 255) / 256, 256, 0, stream>>>(edge, cnt);
    scan_k  <<<1, 1024, 0, stream>>>(cnt, rowptr, cursor, dinv);
    fill_k  <<<(N_EDGES + N_NODES + 255) / 256, 256, 0, stream>>>(edge, cursor, colidx);

    // GCN
    gemm1   <<<(N_NODES + 3) / 4, 256, 0, stream>>>(x, W_gcn, h);
    gcn_agg <<<(N_NODES + 3) / 4, 256, 0, stream>>>(h, rowptr, colidx, dinv, b_gcn, h1);

    // GAT
    gemm2_att<<<(N_NODES + 31) / 32, 256, 0, stream>>>(h1, W_gat, att_s, att_d, hg, as_a, ad_a);
    gat_agg  <<<N_NODES, 256, 0, stream>>>(hg, rowptr, colidx, as_a, ad_a, b_gat, h2);

    // FC
    gemm3   <<<(N_NODES + 7) / 8, 256, 0, stream>>>(h2, W_fc, b_fc, out);
}

// Round 2
// 756.086 us; speedup vs baseline: 1.2915x; 1.2915x over previous
//
#include <hip/hip_runtime.h>
#include <hip/hip_bf16.h>
#include <math.h>

#define N_NODES 50000
#define N_EDGES 1600000
#define D_IN    32
#define HID     64
#define HEADS   4
#define D_OUT   32
#define NEG_SLOPE 0.2f
#define NB 196   // ceil(N_NODES/256)

// ---------------------------------------------------------------- CSR build
__global__ __launch_bounds__(256) void init_cnt(int* __restrict__ cnt) {
    int i = blockIdx.x * 256 + threadIdx.x;
    if (i < N_NODES) cnt[i] = 1;          // self-loop
}

__global__ __launch_bounds__(256) void count_k(const int* __restrict__ edge,
                                               int* __restrict__ cnt) {
    int i = blockIdx.x * 256 + threadIdx.x;
    if (i < N_EDGES) atomicAdd(&cnt[edge[N_EDGES + i]], 1);
}

// parallel scan, 3 tiny kernels (replaces serial single-block scan)
__global__ __launch_bounds__(256) void blockred_k(const int* __restrict__ cnt,
                                                  int* __restrict__ bsum) {
    int t = threadIdx.x;
    int i = blockIdx.x * 256 + t;
    int v = (i < N_NODES) ? cnt[i] : 0;
#pragma unroll
    for (int off = 32; off; off >>= 1) v += __shfl_xor(v, off);
    __shared__ int ws[4];
    if ((t & 63) == 0) ws[t >> 6] = v;
    __syncthreads();
    if (t == 0) bsum[blockIdx.x] = ws[0] + ws[1] + ws[2] + ws[3];
}

__global__ __launch_bounds__(256) void bscan_k(const int* __restrict__ bsum,
                                               int* __restrict__ boff,
                                               int* __restrict__ rowptr) {
    int t = threadIdx.x, lane = t & 63, wv = t >> 6;
    int v = (t < NB) ? bsum[t] : 0;
    int inc = v;
#pragma unroll
    for (int d = 1; d < 64; d <<= 1) {
        int u = __shfl_up(inc, d);
        if (lane >= d) inc += u;
    }
    __shared__ int ws[4];
    if (lane == 63) ws[wv] = inc;
    __syncthreads();
    int add = 0;
#pragma unroll
    for (int j = 0; j < 4; j++) if (j < wv) add += ws[j];
    inc += add;
    if (t < NB) boff[t] = inc - v;
    if (t == NB - 1) rowptr[N_NODES] = inc;     // == N_EDGES + N_NODES
}

__global__ __launch_bounds__(256) void scatter_k(const int* __restrict__ cnt,
                                                 const int* __restrict__ boff,
                                                 int* __restrict__ rowptr,
                                                 int* __restrict__ cursor,
                                                 float* __restrict__ dinv) {
    int t = threadIdx.x, lane = t & 63, wv = t >> 6;
    int i = blockIdx.x * 256 + t;
    int v = (i < N_NODES) ? cnt[i] : 0;
    int inc = v;
#pragma unroll
    for (int d = 1; d < 64; d <<= 1) {
        int u = __shfl_up(inc, d);
        if (lane >= d) inc += u;
    }
    __shared__ int ws[4];
    if (lane == 63) ws[wv] = inc;
    __syncthreads();
    int add = 0;
#pragma unroll
    for (int j = 0; j < 4; j++) if (j < wv) add += ws[j];
    int exc = boff[blockIdx.x] + inc + add - v;
    if (i < N_NODES) {
        rowptr[i] = exc;
        cursor[i] = exc;
        dinv[i]   = rsqrtf((float)v);
    }
}

__global__ __launch_bounds__(256) void fill_k(const int* __restrict__ edge,
                                              int* __restrict__ cursor,
                                              int* __restrict__ colidx) {
    int i = blockIdx.x * 256 + threadIdx.x;
    if (i < N_EDGES) {
        int s = edge[i], d = edge[N_EDGES + i];
        int p = atomicAdd(&cursor[d], 1);
        colidx[p] = s;
    } else if (i < N_EDGES + N_NODES) {
        int n = i - N_EDGES;
        int p = atomicAdd(&cursor[n], 1);
        colidx[p] = n;                    // self-loop
    }
}

// ---------------------------------------------------------------- GEMM1: h = dinv .* (x @ W_gcn)
__global__ __launch_bounds__(256) void gemm1(const float* __restrict__ x,
                                             const float* __restrict__ W,
                                             const float* __restrict__ dinv,
                                             float* __restrict__ h) {
    __shared__ float Wl[D_IN * HID];      // 8 KB
    int t = threadIdx.x;
    for (int i = t; i < D_IN * HID; i += 256) Wl[i] = W[i];
    __syncthreads();
    int c = t & 63;
    int r = blockIdx.x * 4 + (t >> 6);
    if (r >= N_NODES) return;
    const float4* xr4 = (const float4*)(x + r * D_IN);
    float acc = 0.f;
#pragma unroll
    for (int k4 = 0; k4 < D_IN / 4; k4++) {
        float4 xv = xr4[k4];
        int k = k4 * 4;
        acc += xv.x * Wl[(k+0)*HID + c] + xv.y * Wl[(k+1)*HID + c]
             + xv.z * Wl[(k+2)*HID + c] + xv.w * Wl[(k+3)*HID + c];
    }
    h[r * HID + c] = acc * dinv[r];       // pre-scale by dinv[src]
}

// ---------------------------------------------------------------- GCN aggregate -> h1 (relu)
__global__ __launch_bounds__(256) void gcn_agg(const float* __restrict__ h,
                                               const int* __restrict__ rowptr,
                                               const int* __restrict__ colidx,
                                               const float* __restrict__ dinv,
                                               const float* __restrict__ b,
                                               float* __restrict__ h1) {
    int lane = threadIdx.x & 63;
    int n = blockIdx.x * 4 + (threadIdx.x >> 6);
    if (n >= N_NODES) return;
    int rp = rowptr[n], re = rowptr[n + 1];
    float acc = 0.f;
#pragma unroll 2
    for (int e = rp; e < re; e++) {
        int s = colidx[e];                        // wave-uniform broadcast
        acc += h[s * HID + lane];                 // h pre-scaled by dinv[s]
    }
    float v = acc * dinv[n] + b[lane];
    h1[n * HID + lane] = fmaxf(v, 0.f);
}

// ---------------------------------------------------------------- GEMM2: hg = h1 @ W_gat  + fused attention dots
// hg stored PERMUTED: hg[n*256 + c*4 + hd]  (c = channel, hd = head)
__global__ __launch_bounds__(256) void gemm2_att(const float* __restrict__ h1,
                                                 const float* __restrict__ W,
                                                 const float* __restrict__ att_s,
                                                 const float* __restrict__ att_d,
                                                 float* __restrict__ hg,
                                                 float* __restrict__ as_o,
                                                 float* __restrict__ ad_o) {
    __shared__ float Wp[HID * 256];       // 64 KB
    int t = threadIdx.x, lane = t & 63, wv = t >> 6;
    for (int i = t; i < HID * 256; i += 256) {
        int k = i >> 8, rem = i & 255;
        int j = rem >> 6, l = rem & 63;
        Wp[k * 256 + l * 4 + j] = W[i];
    }
    __syncthreads();
    int r0 = blockIdx.x * 32 + wv * 8;
    float hreg[8];
#pragma unroll
    for (int r = 0; r < 8; r++)
        hreg[r] = (r0 + r < N_NODES) ? h1[(r0 + r) * HID + lane] : 0.f;
    float acc[8][4];
#pragma unroll
    for (int r = 0; r < 8; r++)
#pragma unroll
        for (int j = 0; j < 4; j++) acc[r][j] = 0.f;

#pragma unroll 16
    for (int k = 0; k < HID; k++) {
        float4 w4 = *(const float4*)&Wp[k * 256 + lane * 4];   // b128, conflict-free
#pragma unroll
        for (int r = 0; r < 8; r++) {
            float s = __int_as_float(__builtin_amdgcn_readlane(__float_as_int(hreg[r]), k));
            acc[r][0] += s * w4.x;
            acc[r][1] += s * w4.y;
            acc[r][2] += s * w4.z;
            acc[r][3] += s * w4.w;
        }
    }
    // store hg permuted: one dwordx4 per row per lane
#pragma unroll
    for (int r = 0; r < 8; r++) {
        if (r0 + r < N_NODES) {
            float4 v = make_float4(acc[r][0], acc[r][1], acc[r][2], acc[r][3]);
            *(float4*)&hg[(r0 + r) * 256 + lane * 4] = v;
        }
    }
    // fused attention dots
    float attS[4], attD[4];
#pragma unroll
    for (int j = 0; j < 4; j++) { attS[j] = att_s[j * 64 + lane]; attD[j] = att_d[j * 64 + lane]; }
#pragma unroll
    for (int r = 0; r < 8; r++) {
#pragma unroll
        for (int j = 0; j < 4; j++) {
            float vs = acc[r][j] * attS[j];
            float vd = acc[r][j] * attD[j];
#pragma unroll
            for (int off = 32; off > 0; off >>= 1) {
                vs += __shfl_xor(vs, off);
                vd += __shfl_xor(vd, off);
            }
            if (lane == 0 && r0 + r < N_NODES) {
                as_o[(r0 + r) * 4 + j] = vs;
                ad_o[(r0 + r) * 4 + j] = vd;
            }
        }
    }
}

// ---------------------------------------------------------------- GAT aggregate: ONE wave per node, 4 heads vectorized
// h2 stored PERMUTED: h2[n*256 + c*4 + hd]
__global__ __launch_bounds__(256) void gat_agg(const float* __restrict__ hg,
                                               const int* __restrict__ rowptr,
                                               const int* __restrict__ colidx,
                                               const float* __restrict__ a_s,
                                               const float* __restrict__ a_d,
                                               const float* __restrict__ b,
                                               float* __restrict__ h2) {
    int lane = threadIdx.x & 63;
    int n = blockIdx.x * 4 + (threadIdx.x >> 6);
    if (n >= N_NODES) return;
    int rp = rowptr[n], re = rowptr[n + 1];
    float4 ad4 = *(const float4*)&a_d[n * 4];
    // pass 1: per-head segment max (lanes stride edges)
    float mx = -1e30f, my = -1e30f, mz = -1e30f, mw = -1e30f;
    for (int e = rp + lane; e < re; e += 64) {
        int s = colidx[e];
        float4 a = *(const float4*)&a_s[s * 4];
        float vx = a.x + ad4.x; vx = vx > 0.f ? vx : NEG_SLOPE * vx; mx = fmaxf(mx, vx);
        float vy = a.y + ad4.y; vy = vy > 0.f ? vy : NEG_SLOPE * vy; my = fmaxf(my, vy);
        float vz = a.z + ad4.z; vz = vz > 0.f ? vz : NEG_SLOPE * vz; mz = fmaxf(mz, vz);
        float vw = a.w + ad4.w; vw = vw > 0.f ? vw : NEG_SLOPE * vw; mw = fmaxf(mw, vw);
    }
#pragma unroll
    for (int off = 32; off > 0; off >>= 1) {
        mx = fmaxf(mx, __shfl_xor(mx, off));
        my = fmaxf(my, __shfl_xor(my, off));
        mz = fmaxf(mz, __shfl_xor(mz, off));
        mw = fmaxf(mw, __shfl_xor(mw, off));
    }
    // pass 2: weighted sum, all 4 heads per lane
    float dnx = 0.f, dny = 0.f, dnz = 0.f, dnw = 0.f;
    float acx = 0.f, acy = 0.f, acz = 0.f, acw = 0.f;
#pragma unroll 2
    for (int e = rp; e < re; e++) {
        int s = colidx[e];                               // wave-uniform
        float4 a = *(const float4*)&a_s[s * 4];          // 16B broadcast
        float4 g = *(const float4*)&hg[s * 256 + lane * 4];  // coalesced 1KB dwordx4
        float vx = a.x + ad4.x; vx = vx > 0.f ? vx : NEG_SLOPE * vx;
        float vy = a.y + ad4.y; vy = vy > 0.f ? vy : NEG_SLOPE * vy;
        float vz = a.z + ad4.z; vz = vz > 0.f ? vz : NEG_SLOPE * vz;
        float vw = a.w + ad4.w; vw = vw > 0.f ? vw : NEG_SLOPE * vw;
        float wx = __expf(vx - mx), wy = __expf(vy - my);
        float wz = __expf(vz - mz), ww = __expf(vw - mw);
        dnx += wx; dny += wy; dnz += wz; dnw += ww;
        acx += wx * g.x; acy += wy * g.y; acz += wz * g.z; acw += ww * g.w;
    }
    float4 o;
    o.x = fmaxf(acx / dnx + b[0 * 64 + lane], 0.f);
    o.y = fmaxf(acy / dny + b[1 * 64 + lane], 0.f);
    o.z = fmaxf(acz / dnz + b[2 * 64 + lane], 0.f);
    o.w = fmaxf(acw / dnw + b[3 * 64 + lane], 0.f);
    *(float4*)&h2[n * 256 + lane * 4] = o;
}

// ---------------------------------------------------------------- GEMM3: out = h2 @ W_fc + b_fc (h2 permuted; permute W rows to match)
__global__ __launch_bounds__(256) void gemm3(const float* __restrict__ h2,
                                             const float* __restrict__ W,
                                             const float* __restrict__ b,
                                             float* __restrict__ out) {
    __shared__ float Wl[256 * D_OUT];     // 32 KB, rows permuted: Wl[(c*4+hd)*32+j] = W[(hd*64+c)*32+j]
    int t = threadIdx.x;
    for (int i = t; i < 256 * D_OUT; i += 256) {
        int kk = i >> 5, j = i & 31;
        int hd = kk >> 6, c = kk & 63;
        Wl[((c << 2) | hd) * D_OUT + j] = W[i];
    }
    __syncthreads();
    int c = t & 31;
    int r = blockIdx.x * 8 + (t >> 5);
    if (r >= N_NODES) return;
    const float4* hr4 = (const float4*)(h2 + r * 256);
    float acc = b[c];
#pragma unroll 8
    for (int k4 = 0; k4 < 64; k4++) {
        float4 hv = hr4[k4];
        int k = k4 * 4;
        acc += hv.x * Wl[(k+0)*D_OUT + c] + hv.y * Wl[(k+1)*D_OUT + c]
             + hv.z * Wl[(k+2)*D_OUT + c] + hv.w * Wl[(k+3)*D_OUT + c];
    }
    out[r * D_OUT + c] = acc;
}

// ---------------------------------------------------------------- launch
extern "C" void kernel_launch(void* const* d_in, const int* in_sizes, int n_in,
                              void* d_out, int out_size, void* d_ws, size_t ws_size,
                              hipStream_t stream) {
    const float* x      = (const float*)d_in[0];
    const int*   edge   = (const int*)  d_in[1];
    const float* W_gcn  = (const float*)d_in[2];
    const float* b_gcn  = (const float*)d_in[3];
    const float* W_gat  = (const float*)d_in[4];
    const float* att_s  = (const float*)d_in[5];
    const float* att_d  = (const float*)d_in[6];
    const float* b_gat  = (const float*)d_in[7];
    const float* W_fc   = (const float*)d_in[8];
    const float* b_fc   = (const float*)d_in[9];
    float* out = (float*)d_out;

    char* p = (char*)d_ws;
    auto alloc = [&](size_t bytes) {
        char* q = p;
        p += (bytes + 255) & ~(size_t)255;
        return q;
    };
    float* h      = (float*)alloc((size_t)N_NODES * HID * 4);
    float* h1     = (float*)alloc((size_t)N_NODES * HID * 4);
    float* hg     = (float*)alloc((size_t)N_NODES * 256 * 4);
    float* h2     = (float*)alloc((size_t)N_NODES * 256 * 4);
    float* as_a   = (float*)alloc((size_t)N_NODES * 4 * 4);
    float* ad_a   = (float*)alloc((size_t)N_NODES * 4 * 4);
    float* dinv   = (float*)alloc((size_t)N_NODES * 4);
    int*   cnt    = (int*)  alloc((size_t)N_NODES * 4);
    int*   rowptr = (int*)  alloc((size_t)(N_NODES + 1) * 4);
    int*   cursor = (int*)  alloc((size_t)N_NODES * 4);
    int*   colidx = (int*)  alloc((size_t)(N_EDGES + N_NODES) * 4);
    int*   bsum   = (int*)  alloc((size_t)NB * 4);
    int*   boff   = (int*)  alloc((size_t)NB * 4);

    // CSR build
    init_cnt  <<<(N_NODES + 255) / 256, 256, 0, stream>>>(cnt);
    count_k   <<<(N_EDGES + 255) / 256, 256, 0, stream>>>(edge, cnt);
    blockred_k<<<NB, 256, 0, stream>>>(cnt, bsum);
    bscan_k   <<<1, 256, 0, stream>>>(bsum, boff, rowptr);
    scatter_k <<<NB, 256, 0, stream>>>(cnt, boff, rowptr, cursor, dinv);
    fill_k    <<<(N_EDGES + N_NODES + 255) / 256, 256, 0, stream>>>(edge, cursor, colidx);

    // GCN
    gemm1   <<<(N_NODES + 3) / 4, 256, 0, stream>>>(x, W_gcn, dinv, h);
    gcn_agg <<<(N_NODES + 3) / 4, 256, 0, stream>>>(h, rowptr, colidx, dinv, b_gcn, h1);

    // GAT
    gemm2_att<<<(N_NODES + 31) / 32, 256, 0, stream>>>(h1, W_gat, att_s, att_d, hg, as_a, ad_a);
    gat_agg  <<<(N_NODES + 3) / 4, 256, 0, stream>>>(hg, rowptr, colidx, as_a, ad_a, b_gat, h2);

    // FC
    gemm3   <<<(N_NODES + 7) / 8, 256, 0, stream>>>(h2, W_fc, b_fc, out);
}

// Round 3
// 738.338 us; speedup vs baseline: 1.3226x; 1.0240x over previous
//
#include <hip/hip_runtime.h>
#include <hip/hip_bf16.h>
#include <math.h>

#define N_NODES 50000
#define N_EDGES 1600000
#define D_IN    32
#define HID     64
#define HEADS   4
#define D_OUT   32
#define NEG_SLOPE 0.2f
#define NB 196   // ceil(N_NODES/256)
#define CHUNK 128

// ---------------------------------------------------------------- CSR build
__global__ __launch_bounds__(256) void init_cnt(int* __restrict__ cnt) {
    int i = blockIdx.x * 256 + threadIdx.x;
    if (i < N_NODES) cnt[i] = 1;          // self-loop
}

__global__ __launch_bounds__(256) void count_k(const int* __restrict__ edge,
                                               int* __restrict__ cnt) {
    int i = blockIdx.x * 256 + threadIdx.x;
    if (i < N_EDGES) atomicAdd(&cnt[edge[N_EDGES + i]], 1);
}

__global__ __launch_bounds__(256) void blockred_k(const int* __restrict__ cnt,
                                                  int* __restrict__ bsum) {
    int t = threadIdx.x;
    int i = blockIdx.x * 256 + t;
    int v = (i < N_NODES) ? cnt[i] : 0;
#pragma unroll
    for (int off = 32; off; off >>= 1) v += __shfl_xor(v, off);
    __shared__ int ws[4];
    if ((t & 63) == 0) ws[t >> 6] = v;
    __syncthreads();
    if (t == 0) bsum[blockIdx.x] = ws[0] + ws[1] + ws[2] + ws[3];
}

__global__ __launch_bounds__(256) void bscan_k(const int* __restrict__ bsum,
                                               int* __restrict__ boff,
                                               int* __restrict__ rowptr) {
    int t = threadIdx.x, lane = t & 63, wv = t >> 6;
    int v = (t < NB) ? bsum[t] : 0;
    int inc = v;
#pragma unroll
    for (int d = 1; d < 64; d <<= 1) {
        int u = __shfl_up(inc, d);
        if (lane >= d) inc += u;
    }
    __shared__ int ws[4];
    if (lane == 63) ws[wv] = inc;
    __syncthreads();
    int add = 0;
#pragma unroll
    for (int j = 0; j < 4; j++) if (j < wv) add += ws[j];
    inc += add;
    if (t < NB) boff[t] = inc - v;
    if (t == NB - 1) rowptr[N_NODES] = inc;     // == N_EDGES + N_NODES
}

__global__ __launch_bounds__(256) void scatter_k(const int* __restrict__ cnt,
                                                 const int* __restrict__ boff,
                                                 int* __restrict__ rowptr,
                                                 int* __restrict__ cursor,
                                                 float* __restrict__ dinv) {
    int t = threadIdx.x, lane = t & 63, wv = t >> 6;
    int i = blockIdx.x * 256 + t;
    int v = (i < N_NODES) ? cnt[i] : 0;
    int inc = v;
#pragma unroll
    for (int d = 1; d < 64; d <<= 1) {
        int u = __shfl_up(inc, d);
        if (lane >= d) inc += u;
    }
    __shared__ int ws[4];
    if (lane == 63) ws[wv] = inc;
    __syncthreads();
    int add = 0;
#pragma unroll
    for (int j = 0; j < 4; j++) if (j < wv) add += ws[j];
    int exc = boff[blockIdx.x] + inc + add - v;
    if (i < N_NODES) {
        rowptr[i] = exc;
        cursor[i] = exc;
        dinv[i]   = rsqrtf((float)v);
    }
}

__global__ __launch_bounds__(256) void fill_k(const int* __restrict__ edge,
                                              int* __restrict__ cursor,
                                              int* __restrict__ colidx) {
    int i = blockIdx.x * 256 + threadIdx.x;
    if (i < N_EDGES) {
        int s = edge[i], d = edge[N_EDGES + i];
        int p = atomicAdd(&cursor[d], 1);
        colidx[p] = s;
    } else if (i < N_EDGES + N_NODES) {
        int n = i - N_EDGES;
        int p = atomicAdd(&cursor[n], 1);
        colidx[p] = n;                    // self-loop
    }
}

// ---------------------------------------------------------------- GEMM1: h = dinv .* (x @ W_gcn)   32 rows/block
__global__ __launch_bounds__(256) void gemm1(const float* __restrict__ x,
                                             const float* __restrict__ W,
                                             const float* __restrict__ dinv,
                                             float* __restrict__ h) {
    __shared__ float Wl[D_IN * HID];      // 8 KB
    int t = threadIdx.x;
    for (int i = t; i < D_IN * HID; i += 256) Wl[i] = W[i];
    __syncthreads();
    int c = t & 63, rw = t >> 6;
    int r0 = blockIdx.x * 32;
#pragma unroll
    for (int rr = 0; rr < 8; rr++) {
        int r = r0 + rr * 4 + rw;
        if (r >= N_NODES) break;
        const float4* xr4 = (const float4*)(x + r * D_IN);
        float acc = 0.f;
#pragma unroll
        for (int k4 = 0; k4 < D_IN / 4; k4++) {
            float4 xv = xr4[k4];
            int k = k4 * 4;
            acc += xv.x * Wl[(k+0)*HID + c] + xv.y * Wl[(k+1)*HID + c]
                 + xv.z * Wl[(k+2)*HID + c] + xv.w * Wl[(k+3)*HID + c];
        }
        h[r * HID + c] = acc * dinv[r];   // pre-scale by dinv[src]
    }
}

// ---------------------------------------------------------------- GCN aggregate -> h1 (relu)
__global__ __launch_bounds__(256) void gcn_agg(const float* __restrict__ h,
                                               const int* __restrict__ rowptr,
                                               const int* __restrict__ colidx,
                                               const float* __restrict__ dinv,
                                               const float* __restrict__ b,
                                               float* __restrict__ h1) {
    int lane = threadIdx.x & 63;
    int n = blockIdx.x * 4 + (threadIdx.x >> 6);
    if (n >= N_NODES) return;
    int rp = rowptr[n], re = rowptr[n + 1];
    float acc = 0.f;
#pragma unroll 2
    for (int e = rp; e < re; e++) {
        int s = colidx[e];                        // wave-uniform broadcast
        acc += h[s * HID + lane];                 // h pre-scaled by dinv[s]
    }
    float v = acc * dinv[n] + b[lane];
    h1[n * HID + lane] = fmaxf(v, 0.f);
}

// ---------------------------------------------------------------- GEMM2: hg = h1 @ W_gat  + fused attention dots
// hg stored PERMUTED: hg[n*256 + c*4 + hd]
__global__ __launch_bounds__(256) void gemm2_att(const float* __restrict__ h1,
                                                 const float* __restrict__ W,
                                                 const float* __restrict__ att_s,
                                                 const float* __restrict__ att_d,
                                                 float* __restrict__ hg,
                                                 float* __restrict__ as_o,
                                                 float* __restrict__ ad_o) {
    __shared__ float Wp[HID * 256];       // 64 KB
    int t = threadIdx.x, lane = t & 63, wv = t >> 6;
    for (int i = t; i < HID * 256; i += 256) {
        int k = i >> 8, rem = i & 255;
        int j = rem >> 6, l = rem & 63;
        Wp[k * 256 + l * 4 + j] = W[i];
    }
    __syncthreads();
    int r0 = blockIdx.x * 32 + wv * 8;
    float hreg[8];
#pragma unroll
    for (int r = 0; r < 8; r++)
        hreg[r] = (r0 + r < N_NODES) ? h1[(r0 + r) * HID + lane] : 0.f;
    float acc[8][4];
#pragma unroll
    for (int r = 0; r < 8; r++)
#pragma unroll
        for (int j = 0; j < 4; j++) acc[r][j] = 0.f;

#pragma unroll 16
    for (int k = 0; k < HID; k++) {
        float4 w4 = *(const float4*)&Wp[k * 256 + lane * 4];   // b128, conflict-free
#pragma unroll
        for (int r = 0; r < 8; r++) {
            float s = __int_as_float(__builtin_amdgcn_readlane(__float_as_int(hreg[r]), k));
            acc[r][0] += s * w4.x;
            acc[r][1] += s * w4.y;
            acc[r][2] += s * w4.z;
            acc[r][3] += s * w4.w;
        }
    }
#pragma unroll
    for (int r = 0; r < 8; r++) {
        if (r0 + r < N_NODES) {
            float4 v = make_float4(acc[r][0], acc[r][1], acc[r][2], acc[r][3]);
            *(float4*)&hg[(r0 + r) * 256 + lane * 4] = v;
        }
    }
    float attS[4], attD[4];
#pragma unroll
    for (int j = 0; j < 4; j++) { attS[j] = att_s[j * 64 + lane]; attD[j] = att_d[j * 64 + lane]; }
#pragma unroll
    for (int r = 0; r < 8; r++) {
#pragma unroll
        for (int j = 0; j < 4; j++) {
            float vs = acc[r][j] * attS[j];
            float vd = acc[r][j] * attD[j];
#pragma unroll
            for (int off = 32; off > 0; off >>= 1) {
                vs += __shfl_xor(vs, off);
                vd += __shfl_xor(vd, off);
            }
            if (lane == 0 && r0 + r < N_NODES) {
                as_o[(r0 + r) * 4 + j] = vs;
                ad_o[(r0 + r) * 4 + j] = vd;
            }
        }
    }
}

// ---------------------------------------------------------------- GAT aggregate: wave per node, LDS-staged edge weights
// Phase A: distributed max.  Phase B: distributed w=exp(leaky-m) -> LDS + den partials.
// Phase C: serial gather, w broadcast from LDS, 4 FMA/edge.  No __syncthreads (wave-private slices).
__global__ __launch_bounds__(256) void gat_agg(const float* __restrict__ hg,
                                               const int* __restrict__ rowptr,
                                               const int* __restrict__ colidx,
                                               const float* __restrict__ a_s,
                                               const float* __restrict__ a_d,
                                               const float* __restrict__ b,
                                               float* __restrict__ h2) {
    __shared__ float wbuf[4][CHUNK * 4];  // 8 KB
    __shared__ int   sbuf[4][CHUNK];      // 2 KB
    int lane = threadIdx.x & 63;
    int wv = threadIdx.x >> 6;
    int n = blockIdx.x * 4 + wv;
    if (n >= N_NODES) return;
    int rp = rowptr[n], re = rowptr[n + 1];
    float4 ad4 = *(const float4*)&a_d[n * 4];

    // ---- phase A: distributed per-head max
    float mx = -1e30f, my = -1e30f, mz = -1e30f, mw = -1e30f;
    for (int e = rp + lane; e < re; e += 64) {
        int s = colidx[e];
        float4 a = *(const float4*)&a_s[s * 4];
        float vx = a.x + ad4.x; vx = fmaxf(vx, NEG_SLOPE * vx); mx = fmaxf(mx, vx);
        float vy = a.y + ad4.y; vy = fmaxf(vy, NEG_SLOPE * vy); my = fmaxf(my, vy);
        float vz = a.z + ad4.z; vz = fmaxf(vz, NEG_SLOPE * vz); mz = fmaxf(mz, vz);
        float vw = a.w + ad4.w; vw = fmaxf(vw, NEG_SLOPE * vw); mw = fmaxf(mw, vw);
    }
#pragma unroll
    for (int off = 32; off > 0; off >>= 1) {
        mx = fmaxf(mx, __shfl_xor(mx, off));
        my = fmaxf(my, __shfl_xor(my, off));
        mz = fmaxf(mz, __shfl_xor(mz, off));
        mw = fmaxf(mw, __shfl_xor(mw, off));
    }

    // ---- phases B/C, chunked
    float dnx = 0.f, dny = 0.f, dnz = 0.f, dnw = 0.f;
    float acx = 0.f, acy = 0.f, acz = 0.f, acw = 0.f;
    const float* gp = hg + lane * 4;
    for (int cb = rp; cb < re; cb += CHUNK) {
        int ce = min(cb + CHUNK, re);
        // phase B: distributed weight computation -> LDS
        for (int e = cb + lane; e < ce; e += 64) {
            int s = colidx[e];
            float4 a = *(const float4*)&a_s[s * 4];
            float vx = a.x + ad4.x; vx = fmaxf(vx, NEG_SLOPE * vx);
            float vy = a.y + ad4.y; vy = fmaxf(vy, NEG_SLOPE * vy);
            float vz = a.z + ad4.z; vz = fmaxf(vz, NEG_SLOPE * vz);
            float vw = a.w + ad4.w; vw = fmaxf(vw, NEG_SLOPE * vw);
            float wx = __expf(vx - mx), wy = __expf(vy - my);
            float wz = __expf(vz - mz), ww = __expf(vw - mw);
            dnx += wx; dny += wy; dnz += wz; dnw += ww;
            int idx = e - cb;
            *(float4*)&wbuf[wv][idx * 4] = make_float4(wx, wy, wz, ww);
            sbuf[wv][idx] = s;
        }
        // phase C: serial gather (LDS broadcast reads, compiler-inserted lgkmcnt orders B->C)
        int cnt_c = ce - cb;
#pragma unroll 2
        for (int idx = 0; idx < cnt_c; idx++) {
            int s = sbuf[wv][idx];
            float4 w4 = *(const float4*)&wbuf[wv][idx * 4];
            float4 g = *(const float4*)&gp[s * 256];        // coalesced dwordx4
            acx += w4.x * g.x; acy += w4.y * g.y;
            acz += w4.z * g.z; acw += w4.w * g.w;
        }
    }
    // reduce denominators across lanes
#pragma unroll
    for (int off = 32; off > 0; off >>= 1) {
        dnx += __shfl_xor(dnx, off);
        dny += __shfl_xor(dny, off);
        dnz += __shfl_xor(dnz, off);
        dnw += __shfl_xor(dnw, off);
    }
    float4 o;
    o.x = fmaxf(acx / dnx + b[0 * 64 + lane], 0.f);
    o.y = fmaxf(acy / dny + b[1 * 64 + lane], 0.f);
    o.z = fmaxf(acz / dnz + b[2 * 64 + lane], 0.f);
    o.w = fmaxf(acw / dnw + b[3 * 64 + lane], 0.f);
    *(float4*)&h2[n * 256 + lane * 4] = o;
}

// ---------------------------------------------------------------- GEMM3: out = h2 @ W_fc + b_fc   32 rows/block
__global__ __launch_bounds__(256) void gemm3(const float* __restrict__ h2,
                                             const float* __restrict__ W,
                                             const float* __restrict__ b,
                                             float* __restrict__ out) {
    __shared__ float Wl[256 * D_OUT];     // 32 KB, rows permuted to h2 layout
    int t = threadIdx.x;
    for (int i = t; i < 256 * D_OUT; i += 256) {
        int kk = i >> 5, j = i & 31;
        int hd = kk >> 6, c = kk & 63;
        Wl[((c << 2) | hd) * D_OUT + j] = W[i];
    }
    __syncthreads();
    int c = t & 31, rw = t >> 5;
    int r0 = blockIdx.x * 32;
#pragma unroll
    for (int rr = 0; rr < 4; rr++) {
        int r = r0 + rr * 8 + rw;
        if (r >= N_NODES) break;
        const float4* hr4 = (const float4*)(h2 + r * 256);
        float acc = b[c];
#pragma unroll 8
        for (int k4 = 0; k4 < 64; k4++) {
            float4 hv = hr4[k4];
            int k = k4 * 4;
            acc += hv.x * Wl[(k+0)*D_OUT + c] + hv.y * Wl[(k+1)*D_OUT + c]
                 + hv.z * Wl[(k+2)*D_OUT + c] + hv.w * Wl[(k+3)*D_OUT + c];
        }
        out[r * D_OUT + c] = acc;
    }
}

// ---------------------------------------------------------------- launch
extern "C" void kernel_launch(void* const* d_in, const int* in_sizes, int n_in,
                              void* d_out, int out_size, void* d_ws, size_t ws_size,
                              hipStream_t stream) {
    const float* x      = (const float*)d_in[0];
    const int*   edge   = (const int*)  d_in[1];
    const float* W_gcn  = (const float*)d_in[2];
    const float* b_gcn  = (const float*)d_in[3];
    const float* W_gat  = (const float*)d_in[4];
    const float* att_s  = (const float*)d_in[5];
    const float* att_d  = (const float*)d_in[6];
    const float* b_gat  = (const float*)d_in[7];
    const float* W_fc   = (const float*)d_in[8];
    const float* b_fc   = (const float*)d_in[9];
    float* out = (float*)d_out;

    char* p = (char*)d_ws;
    auto alloc = [&](size_t bytes) {
        char* q = p;
        p += (bytes + 255) & ~(size_t)255;
        return q;
    };
    float* h      = (float*)alloc((size_t)N_NODES * HID * 4);
    float* h1     = (float*)alloc((size_t)N_NODES * HID * 4);
    float* hg     = (float*)alloc((size_t)N_NODES * 256 * 4);
    float* h2     = (float*)alloc((size_t)N_NODES * 256 * 4);
    float* as_a   = (float*)alloc((size_t)N_NODES * 4 * 4);
    float* ad_a   = (float*)alloc((size_t)N_NODES * 4 * 4);
    float* dinv   = (float*)alloc((size_t)N_NODES * 4);
    int*   cnt    = (int*)  alloc((size_t)N_NODES * 4);
    int*   rowptr = (int*)  alloc((size_t)(N_NODES + 1) * 4);
    int*   cursor = (int*)  alloc((size_t)N_NODES * 4);
    int*   colidx = (int*)  alloc((size_t)(N_EDGES + N_NODES) * 4);
    int*   bsum   = (int*)  alloc((size_t)NB * 4);
    int*   boff   = (int*)  alloc((size_t)NB * 4);

    // CSR build
    init_cnt  <<<(N_NODES + 255) / 256, 256, 0, stream>>>(cnt);
    count_k   <<<(N_EDGES + 255) / 256, 256, 0, stream>>>(edge, cnt);
    blockred_k<<<NB, 256, 0, stream>>>(cnt, bsum);
    bscan_k   <<<1, 256, 0, stream>>>(bsum, boff, rowptr);
    scatter_k <<<NB, 256, 0, stream>>>(cnt, boff, rowptr, cursor, dinv);
    fill_k    <<<(N_EDGES + N_NODES + 255) / 256, 256, 0, stream>>>(edge, cursor, colidx);

    // GCN
    gemm1   <<<(N_NODES + 31) / 32, 256, 0, stream>>>(x, W_gcn, dinv, h);
    gcn_agg <<<(N_NODES + 3) / 4, 256, 0, stream>>>(h, rowptr, colidx, dinv, b_gcn, h1);

    // GAT
    gemm2_att<<<(N_NODES + 31) / 32, 256, 0, stream>>>(h1, W_gat, att_s, att_d, hg, as_a, ad_a);
    gat_agg  <<<(N_NODES + 3) / 4, 256, 0, stream>>>(hg, rowptr, colidx, as_a, ad_a, b_gat, h2);

    // FC
    gemm3   <<<(N_NODES + 31) / 32, 256, 0, stream>>>(h2, W_fc, b_fc, out);
}

// Round 4
// 576.829 us; speedup vs baseline: 1.6929x; 1.2800x over previous
//
#include <hip/hip_runtime.h>
#include <hip/hip_bf16.h>
#include <math.h>

#define N_NODES 50000
#define N_EDGES 1600000
#define D_IN    32
#define HID     64
#define HEADS   4
#define D_OUT   32
#define NEG_SLOPE 0.2f
#define NB 196   // ceil(N_NODES/256)
#define CHUNK 128

// ---------------------------------------------------------------- CSR build
__global__ __launch_bounds__(256) void init_cnt(int* __restrict__ cnt) {
    int i = blockIdx.x * 256 + threadIdx.x;
    if (i < N_NODES) cnt[i] = 1;          // self-loop
}

__global__ __launch_bounds__(256) void count_k(const int* __restrict__ edge,
                                               int* __restrict__ cnt) {
    int i = blockIdx.x * 256 + threadIdx.x;
    if (i < N_EDGES) atomicAdd(&cnt[edge[N_EDGES + i]], 1);
}

__global__ __launch_bounds__(256) void blockred_k(const int* __restrict__ cnt,
                                                  int* __restrict__ bsum) {
    int t = threadIdx.x;
    int i = blockIdx.x * 256 + t;
    int v = (i < N_NODES) ? cnt[i] : 0;
#pragma unroll
    for (int off = 32; off; off >>= 1) v += __shfl_xor(v, off);
    __shared__ int ws[4];
    if ((t & 63) == 0) ws[t >> 6] = v;
    __syncthreads();
    if (t == 0) bsum[blockIdx.x] = ws[0] + ws[1] + ws[2] + ws[3];
}

__global__ __launch_bounds__(256) void bscan_k(const int* __restrict__ bsum,
                                               int* __restrict__ boff,
                                               int* __restrict__ rowptr) {
    int t = threadIdx.x, lane = t & 63, wv = t >> 6;
    int v = (t < NB) ? bsum[t] : 0;
    int inc = v;
#pragma unroll
    for (int d = 1; d < 64; d <<= 1) {
        int u = __shfl_up(inc, d);
        if (lane >= d) inc += u;
    }
    __shared__ int ws[4];
    if (lane == 63) ws[wv] = inc;
    __syncthreads();
    int add = 0;
#pragma unroll
    for (int j = 0; j < 4; j++) if (j < wv) add += ws[j];
    inc += add;
    if (t < NB) boff[t] = inc - v;
    if (t == NB - 1) rowptr[N_NODES] = inc;     // == N_EDGES + N_NODES
}

__global__ __launch_bounds__(256) void scatter_k(const int* __restrict__ cnt,
                                                 const int* __restrict__ boff,
                                                 int* __restrict__ rowptr,
                                                 int* __restrict__ cursor,
                                                 float* __restrict__ dinv) {
    int t = threadIdx.x, lane = t & 63, wv = t >> 6;
    int i = blockIdx.x * 256 + t;
    int v = (i < N_NODES) ? cnt[i] : 0;
    int inc = v;
#pragma unroll
    for (int d = 1; d < 64; d <<= 1) {
        int u = __shfl_up(inc, d);
        if (lane >= d) inc += u;
    }
    __shared__ int ws[4];
    if (lane == 63) ws[wv] = inc;
    __syncthreads();
    int add = 0;
#pragma unroll
    for (int j = 0; j < 4; j++) if (j < wv) add += ws[j];
    int exc = boff[blockIdx.x] + inc + add - v;
    if (i < N_NODES) {
        rowptr[i] = exc;
        cursor[i] = exc;
        dinv[i]   = rsqrtf((float)v);
    }
}

__global__ __launch_bounds__(256) void fill_k(const int* __restrict__ edge,
                                              int* __restrict__ cursor,
                                              int* __restrict__ colidx) {
    int i = blockIdx.x * 256 + threadIdx.x;
    if (i < N_EDGES) {
        int s = edge[i], d = edge[N_EDGES + i];
        int p = atomicAdd(&cursor[d], 1);
        colidx[p] = s;
    } else if (i < N_EDGES + N_NODES) {
        int n = i - N_EDGES;
        int p = atomicAdd(&cursor[n], 1);
        colidx[p] = n;                    // self-loop
    }
}

// ---------------------------------------------------------------- attention projection vectors: vsrc[h][k] = sum_c W[k][h*64+c]*att_s[h][c]
__global__ __launch_bounds__(256) void attvec_k(const float* __restrict__ W,
                                                const float* __restrict__ att_s,
                                                const float* __restrict__ att_d,
                                                float* __restrict__ vsrc,
                                                float* __restrict__ vdst) {
    int t = threadIdx.x;
    int h = t >> 6, k = t & 63;
    float s_ = 0.f, d_ = 0.f;
#pragma unroll 8
    for (int c = 0; c < 64; c++) {
        float w = W[k * 256 + h * 64 + c];
        s_ += w * att_s[h * 64 + c];
        d_ += w * att_d[h * 64 + c];
    }
    vsrc[h * 64 + k] = s_;
    vdst[h * 64 + k] = d_;
}

// ---------------------------------------------------------------- GEMM1: h = dinv .* (x @ W_gcn)   32 rows/block
__global__ __launch_bounds__(256) void gemm1(const float* __restrict__ x,
                                             const float* __restrict__ W,
                                             const float* __restrict__ dinv,
                                             float* __restrict__ h) {
    __shared__ float Wl[D_IN * HID];      // 8 KB
    int t = threadIdx.x;
    for (int i = t; i < D_IN * HID; i += 256) Wl[i] = W[i];
    __syncthreads();
    int c = t & 63, rw = t >> 6;
    int r0 = blockIdx.x * 32;
#pragma unroll
    for (int rr = 0; rr < 8; rr++) {
        int r = r0 + rr * 4 + rw;
        if (r >= N_NODES) break;
        const float4* xr4 = (const float4*)(x + r * D_IN);
        float acc = 0.f;
#pragma unroll
        for (int k4 = 0; k4 < D_IN / 4; k4++) {
            float4 xv = xr4[k4];
            int k = k4 * 4;
            acc += xv.x * Wl[(k+0)*HID + c] + xv.y * Wl[(k+1)*HID + c]
                 + xv.z * Wl[(k+2)*HID + c] + xv.w * Wl[(k+3)*HID + c];
        }
        h[r * HID + c] = acc * dinv[r];   // pre-scale by dinv[src]
    }
}

// ---------------------------------------------------------------- GCN aggregate -> h1 (relu), fused attention dots
__global__ __launch_bounds__(256) void gcn_agg(const float* __restrict__ h,
                                               const int* __restrict__ rowptr,
                                               const int* __restrict__ colidx,
                                               const float* __restrict__ dinv,
                                               const float* __restrict__ b,
                                               const float* __restrict__ vsrc,
                                               const float* __restrict__ vdst,
                                               float* __restrict__ h1,
                                               float* __restrict__ as_o,
                                               float* __restrict__ ad_o) {
    __shared__ int sbuf[4][CHUNK];
    int lane = threadIdx.x & 63, wv = threadIdx.x >> 6;
    int n = blockIdx.x * 4 + wv;
    if (n >= N_NODES) return;
    int rp = rowptr[n], re = rowptr[n + 1];
    float acc = 0.f;
    const float* hp = h + lane;
    for (int cb = rp; cb < re; cb += CHUNK) {
        int ce = min(cb + CHUNK, re);
        for (int e = cb + lane; e < ce; e += 64) sbuf[wv][e - cb] = colidx[e];
        int m = ce - cb;
#pragma unroll 4
        for (int i = 0; i < m; i++)
            acc += hp[sbuf[wv][i] * HID];             // coalesced 256B, h pre-scaled
    }
    float h1v = fmaxf(acc * dinv[n] + b[lane], 0.f);
    h1[n * HID + lane] = h1v;
    // attention dots: a_s[n][h] = h1 . vsrc[h], a_d likewise
#pragma unroll
    for (int hh = 0; hh < 4; hh++) {
        float vs = h1v * vsrc[hh * 64 + lane];
        float vd = h1v * vdst[hh * 64 + lane];
#pragma unroll
        for (int off = 32; off > 0; off >>= 1) {
            vs += __shfl_xor(vs, off);
            vd += __shfl_xor(vd, off);
        }
        if (lane == 0) {
            as_o[n * 4 + hh] = vs;
            ad_o[n * 4 + hh] = vd;
        }
    }
}

// ---------------------------------------------------------------- GAT aggregate over h1 (NOT hg): u[n][h][k] = sum_s w_h * h1[s][k]
// u written pre-divided by denominator.
__global__ __launch_bounds__(256) void gat_agg(const float* __restrict__ h1,
                                               const int* __restrict__ rowptr,
                                               const int* __restrict__ colidx,
                                               const float* __restrict__ a_s,
                                               const float* __restrict__ a_d,
                                               float* __restrict__ u) {
    __shared__ float wbuf[4][CHUNK * 4];  // 8 KB
    __shared__ int   sbuf[4][CHUNK];      // 2 KB
    int lane = threadIdx.x & 63;
    int wv = threadIdx.x >> 6;
    int n = blockIdx.x * 4 + wv;
    if (n >= N_NODES) return;
    int rp = rowptr[n], re = rowptr[n + 1];
    float4 ad4 = *(const float4*)&a_d[n * 4];

    // ---- phase A: distributed per-head max of a_s (leaky is monotone: apply after max)
    float mx = -1e30f, my = -1e30f, mz = -1e30f, mw = -1e30f;
    for (int e = rp + lane; e < re; e += 64) {
        int s = colidx[e];
        float4 a = *(const float4*)&a_s[s * 4];
        mx = fmaxf(mx, a.x); my = fmaxf(my, a.y);
        mz = fmaxf(mz, a.z); mw = fmaxf(mw, a.w);
    }
#pragma unroll
    for (int off = 32; off > 0; off >>= 1) {
        mx = fmaxf(mx, __shfl_xor(mx, off));
        my = fmaxf(my, __shfl_xor(my, off));
        mz = fmaxf(mz, __shfl_xor(mz, off));
        mw = fmaxf(mw, __shfl_xor(mw, off));
    }
    mx += ad4.x; mx = fmaxf(mx, NEG_SLOPE * mx);
    my += ad4.y; my = fmaxf(my, NEG_SLOPE * my);
    mz += ad4.z; mz = fmaxf(mz, NEG_SLOPE * mz);
    mw += ad4.w; mw = fmaxf(mw, NEG_SLOPE * mw);

    // ---- phases B/C, chunked
    float dnx = 0.f, dny = 0.f, dnz = 0.f, dnw = 0.f;
    float ac0 = 0.f, ac1 = 0.f, ac2 = 0.f, ac3 = 0.f;
    const float* hp = h1 + lane;
    for (int cb = rp; cb < re; cb += CHUNK) {
        int ce = min(cb + CHUNK, re);
        // phase B: distributed weight computation -> LDS
        for (int e = cb + lane; e < ce; e += 64) {
            int s = colidx[e];
            float4 a = *(const float4*)&a_s[s * 4];
            float vx = a.x + ad4.x; vx = fmaxf(vx, NEG_SLOPE * vx);
            float vy = a.y + ad4.y; vy = fmaxf(vy, NEG_SLOPE * vy);
            float vz = a.z + ad4.z; vz = fmaxf(vz, NEG_SLOPE * vz);
            float vw = a.w + ad4.w; vw = fmaxf(vw, NEG_SLOPE * vw);
            float wx = __expf(vx - mx), wy = __expf(vy - my);
            float wz = __expf(vz - mz), ww = __expf(vw - mw);
            dnx += wx; dny += wy; dnz += wz; dnw += ww;
            int idx = e - cb;
            *(float4*)&wbuf[wv][idx * 4] = make_float4(wx, wy, wz, ww);
            sbuf[wv][idx] = s;
        }
        // phase C: serial gather of h1 rows (256B/edge), weights broadcast from LDS
        int cnt_c = ce - cb;
#pragma unroll 4
        for (int idx = 0; idx < cnt_c; idx++) {
            int s = sbuf[wv][idx];
            float4 w4 = *(const float4*)&wbuf[wv][idx * 4];
            float g = hp[s * HID];                    // one dword/lane
            ac0 += w4.x * g; ac1 += w4.y * g;
            ac2 += w4.z * g; ac3 += w4.w * g;
        }
    }
    // reduce denominators across lanes
#pragma unroll
    for (int off = 32; off > 0; off >>= 1) {
        dnx += __shfl_xor(dnx, off);
        dny += __shfl_xor(dny, off);
        dnz += __shfl_xor(dnz, off);
        dnw += __shfl_xor(dnw, off);
    }
    float* up = u + n * 256;
    up[0 * 64 + lane] = ac0 / dnx;
    up[1 * 64 + lane] = ac1 / dny;
    up[2 * 64 + lane] = ac2 / dnz;
    up[3 * 64 + lane] = ac3 / dnw;
}

// ---------------------------------------------------------------- gemm2b: h2 = relu(u @ blockdiag(W_gat) + b)   (u pre-divided)
__global__ __launch_bounds__(256) void gemm2b(const float* __restrict__ u,
                                              const float* __restrict__ W,
                                              const float* __restrict__ b,
                                              float* __restrict__ h2) {
    __shared__ float Wl[HID * 256];       // 64 KB, straight copy
    int t = threadIdx.x, lane = t & 63, hd = t >> 6;
    for (int i = t; i < HID * 256; i += 256) Wl[i] = W[i];
    __syncthreads();
    int r0 = blockIdx.x * 8;
    float ureg[8];
#pragma unroll
    for (int r = 0; r < 8; r++)
        ureg[r] = (r0 + r < N_NODES) ? u[(r0 + r) * 256 + hd * 64 + lane] : 0.f;
    float acc[8];
#pragma unroll
    for (int r = 0; r < 8; r++) acc[r] = 0.f;
#pragma unroll 16
    for (int k = 0; k < 64; k++) {
        float w = Wl[k * 256 + hd * 64 + lane];       // 2-way bank alias: free
#pragma unroll
        for (int r = 0; r < 8; r++) {
            float s = __int_as_float(__builtin_amdgcn_readlane(__float_as_int(ureg[r]), k));
            acc[r] += s * w;
        }
    }
    float bb = b[hd * 64 + lane];
#pragma unroll
    for (int r = 0; r < 8; r++)
        if (r0 + r < N_NODES)
            h2[(r0 + r) * 256 + hd * 64 + lane] = fmaxf(acc[r] + bb, 0.f);
}

// ---------------------------------------------------------------- GEMM3: out = h2 @ W_fc + b_fc   32 rows/block
__global__ __launch_bounds__(256) void gemm3(const float* __restrict__ h2,
                                             const float* __restrict__ W,
                                             const float* __restrict__ b,
                                             float* __restrict__ out) {
    __shared__ float Wl[256 * D_OUT];     // 32 KB, straight copy
    int t = threadIdx.x;
    for (int i = t; i < 256 * D_OUT; i += 256) Wl[i] = W[i];
    __syncthreads();
    int c = t & 31, rw = t >> 5;
    int r0 = blockIdx.x * 32;
#pragma unroll
    for (int rr = 0; rr < 4; rr++) {
        int r = r0 + rr * 8 + rw;
        if (r >= N_NODES) break;
        const float4* hr4 = (const float4*)(h2 + r * 256);
        float acc = b[c];
#pragma unroll 8
        for (int k4 = 0; k4 < 64; k4++) {
            float4 hv = hr4[k4];
            int k = k4 * 4;
            acc += hv.x * Wl[(k+0)*D_OUT + c] + hv.y * Wl[(k+1)*D_OUT + c]
                 + hv.z * Wl[(k+2)*D_OUT + c] + hv.w * Wl[(k+3)*D_OUT + c];
        }
        out[r * D_OUT + c] = acc;
    }
}

// ---------------------------------------------------------------- launch
extern "C" void kernel_launch(void* const* d_in, const int* in_sizes, int n_in,
                              void* d_out, int out_size, void* d_ws, size_t ws_size,
                              hipStream_t stream) {
    const float* x      = (const float*)d_in[0];
    const int*   edge   = (const int*)  d_in[1];
    const float* W_gcn  = (const float*)d_in[2];
    const float* b_gcn  = (const float*)d_in[3];
    const float* W_gat  = (const float*)d_in[4];
    const float* att_s  = (const float*)d_in[5];
    const float* att_d  = (const float*)d_in[6];
    const float* b_gat  = (const float*)d_in[7];
    const float* W_fc   = (const float*)d_in[8];
    const float* b_fc   = (const float*)d_in[9];
    float* out = (float*)d_out;

    char* p = (char*)d_ws;
    auto alloc = [&](size_t bytes) {
        char* q = p;
        p += (bytes + 255) & ~(size_t)255;
        return q;
    };
    float* h      = (float*)alloc((size_t)N_NODES * HID * 4);
    float* h1     = (float*)alloc((size_t)N_NODES * HID * 4);
    float* u      = (float*)alloc((size_t)N_NODES * 256 * 4);
    float* h2     = (float*)alloc((size_t)N_NODES * 256 * 4);
    float* as_a   = (float*)alloc((size_t)N_NODES * 4 * 4);
    float* ad_a   = (float*)alloc((size_t)N_NODES * 4 * 4);
    float* dinv   = (float*)alloc((size_t)N_NODES * 4);
    int*   cnt    = (int*)  alloc((size_t)N_NODES * 4);
    int*   rowptr = (int*)  alloc((size_t)(N_NODES + 1) * 4);
    int*   cursor = (int*)  alloc((size_t)N_NODES * 4);
    int*   colidx = (int*)  alloc((size_t)(N_EDGES + N_NODES) * 4);
    int*   bsum   = (int*)  alloc((size_t)NB * 4);
    int*   boff   = (int*)  alloc((size_t)NB * 4);
    float* vsrc   = (float*)alloc((size_t)HEADS * HID * 4);
    float* vdst   = (float*)alloc((size_t)HEADS * HID * 4);

    // CSR build
    init_cnt  <<<(N_NODES + 255) / 256, 256, 0, stream>>>(cnt);
    count_k   <<<(N_EDGES + 255) / 256, 256, 0, stream>>>(edge, cnt);
    blockred_k<<<NB, 256, 0, stream>>>(cnt, bsum);
    bscan_k   <<<1, 256, 0, stream>>>(bsum, boff, rowptr);
    scatter_k <<<NB, 256, 0, stream>>>(cnt, boff, rowptr, cursor, dinv);
    fill_k    <<<(N_EDGES + N_NODES + 255) / 256, 256, 0, stream>>>(edge, cursor, colidx);

    // attention projection vectors
    attvec_k<<<1, 256, 0, stream>>>(W_gat, att_s, att_d, vsrc, vdst);

    // GCN
    gemm1   <<<(N_NODES + 31) / 32, 256, 0, stream>>>(x, W_gcn, dinv, h);
    gcn_agg <<<(N_NODES + 3) / 4, 256, 0, stream>>>(h, rowptr, colidx, dinv, b_gcn,
                                                    vsrc, vdst, h1, as_a, ad_a);

    // GAT (gathers h1, not hg)
    gat_agg <<<(N_NODES + 3) / 4, 256, 0, stream>>>(h1, rowptr, colidx, as_a, ad_a, u);
    gemm2b  <<<(N_NODES + 7) / 8, 256, 0, stream>>>(u, W_gat, b_gat, h2);

    // FC
    gemm3   <<<(N_NODES + 31) / 32, 256, 0, stream>>>(h2, W_fc, b_fc, out);
}

// Round 5
// 457.716 us; speedup vs baseline: 2.1334x; 1.2602x over previous
//
#include <hip/hip_runtime.h>
#include <hip/hip_bf16.h>
#include <hip/hip_fp16.h>
#include <math.h>

#define N_NODES 50000
#define N_EDGES 1600000
#define D_IN    32
#define HID     64
#define HEADS   4
#define D_OUT   32
#define NEG_SLOPE 0.2f
#define NB 196   // ceil(N_NODES/256)
#define CHUNK 128

// ---------------------------------------------------------------- CSR build
__global__ __launch_bounds__(256) void init_cnt(int* __restrict__ cnt) {
    int i = blockIdx.x * 256 + threadIdx.x;
    if (i < N_NODES) cnt[i] = 1;          // slot 0 reserved for self-loop
}

// count + claim per-edge slot (offsets start at 1; slot 0 = self-loop)
__global__ __launch_bounds__(256) void count_k(const int* __restrict__ edge,
                                               int* __restrict__ cnt,
                                               int* __restrict__ eoff) {
    int i = blockIdx.x * 256 + threadIdx.x;
    if (i < N_EDGES) eoff[i] = atomicAdd(&cnt[edge[N_EDGES + i]], 1);
}

__global__ __launch_bounds__(256) void blockred_k(const int* __restrict__ cnt,
                                                  int* __restrict__ bsum) {
    int t = threadIdx.x;
    int i = blockIdx.x * 256 + t;
    int v = (i < N_NODES) ? cnt[i] : 0;
#pragma unroll
    for (int off = 32; off; off >>= 1) v += __shfl_xor(v, off);
    __shared__ int ws[4];
    if ((t & 63) == 0) ws[t >> 6] = v;
    __syncthreads();
    if (t == 0) bsum[blockIdx.x] = ws[0] + ws[1] + ws[2] + ws[3];
}

__global__ __launch_bounds__(256) void bscan_k(const int* __restrict__ bsum,
                                               int* __restrict__ boff,
                                               int* __restrict__ rowptr) {
    int t = threadIdx.x, lane = t & 63, wv = t >> 6;
    int v = (t < NB) ? bsum[t] : 0;
    int inc = v;
#pragma unroll
    for (int d = 1; d < 64; d <<= 1) {
        int u = __shfl_up(inc, d);
        if (lane >= d) inc += u;
    }
    __shared__ int ws[4];
    if (lane == 63) ws[wv] = inc;
    __syncthreads();
    int add = 0;
#pragma unroll
    for (int j = 0; j < 4; j++) if (j < wv) add += ws[j];
    inc += add;
    if (t < NB) boff[t] = inc - v;
    if (t == NB - 1) rowptr[N_NODES] = inc;     // == N_EDGES + N_NODES
}

__global__ __launch_bounds__(256) void scatter_k(const int* __restrict__ cnt,
                                                 const int* __restrict__ boff,
                                                 int* __restrict__ rowptr,
                                                 float* __restrict__ dinv,
                                                 int* __restrict__ colidx) {
    int t = threadIdx.x, lane = t & 63, wv = t >> 6;
    int i = blockIdx.x * 256 + t;
    int v = (i < N_NODES) ? cnt[i] : 0;
    int inc = v;
#pragma unroll
    for (int d = 1; d < 64; d <<= 1) {
        int u = __shfl_up(inc, d);
        if (lane >= d) inc += u;
    }
    __shared__ int ws[4];
    if (lane == 63) ws[wv] = inc;
    __syncthreads();
    int add = 0;
#pragma unroll
    for (int j = 0; j < 4; j++) if (j < wv) add += ws[j];
    int exc = boff[blockIdx.x] + inc + add - v;
    if (i < N_NODES) {
        rowptr[i] = exc;
        dinv[i]   = rsqrtf((float)v);
        colidx[exc] = i;                  // self-loop at slot 0 (coalesced-ish)
    }
}

// pure scatter, no atomics, no dependency chain
__global__ __launch_bounds__(256) void fill2_k(const int* __restrict__ edge,
                                               const int* __restrict__ eoff,
                                               const int* __restrict__ rowptr,
                                               int* __restrict__ colidx) {
    int i = blockIdx.x * 256 + threadIdx.x;
    if (i < N_EDGES) {
        int s = edge[i], d = edge[N_EDGES + i];
        colidx[rowptr[d] + eoff[i]] = s;  // rowptr[d] random read: L2-resident 200KB
    }
}

// ---------------------------------------------------------------- attention projection vectors
__global__ __launch_bounds__(256) void attvec_k(const float* __restrict__ W,
                                                const float* __restrict__ att_s,
                                                const float* __restrict__ att_d,
                                                float* __restrict__ vsrc,
                                                float* __restrict__ vdst) {
    int t = threadIdx.x;
    int h = t >> 6, k = t & 63;
    float s_ = 0.f, d_ = 0.f;
#pragma unroll 8
    for (int c = 0; c < 64; c++) {
        float w = W[k * 256 + h * 64 + c];
        s_ += w * att_s[h * 64 + c];
        d_ += w * att_d[h * 64 + c];
    }
    vsrc[h * 64 + k] = s_;
    vdst[h * 64 + k] = d_;
}

// ---------------------------------------------------------------- GEMM1: h = fp16( dinv .* (x @ W_gcn) )
__global__ __launch_bounds__(256) void gemm1(const float* __restrict__ x,
                                             const float* __restrict__ W,
                                             const float* __restrict__ dinv,
                                             __half* __restrict__ h) {
    __shared__ float Wl[D_IN * HID];      // 8 KB
    int t = threadIdx.x;
    for (int i = t; i < D_IN * HID; i += 256) Wl[i] = W[i];
    __syncthreads();
    int c = t & 63, rw = t >> 6;
    int r0 = blockIdx.x * 32;
#pragma unroll
    for (int rr = 0; rr < 8; rr++) {
        int r = r0 + rr * 4 + rw;
        if (r >= N_NODES) break;
        const float4* xr4 = (const float4*)(x + r * D_IN);
        float acc = 0.f;
#pragma unroll
        for (int k4 = 0; k4 < D_IN / 4; k4++) {
            float4 xv = xr4[k4];
            int k = k4 * 4;
            acc += xv.x * Wl[(k+0)*HID + c] + xv.y * Wl[(k+1)*HID + c]
                 + xv.z * Wl[(k+2)*HID + c] + xv.w * Wl[(k+3)*HID + c];
        }
        h[r * HID + c] = __float2half(acc * dinv[r]);   // pre-scaled by dinv[src]
    }
}

// ---------------------------------------------------------------- GCN aggregate -> h1 fp16 (relu), fused attention dots
// wave = node; 2 edges per iter: lanes 0-31 edge A, lanes 32-63 edge B; lane holds 2 channels (fp16 pair)
__global__ __launch_bounds__(256) void gcn_agg(const __half* __restrict__ h,
                                               const int* __restrict__ rowptr,
                                               const int* __restrict__ colidx,
                                               const float* __restrict__ dinv,
                                               const float* __restrict__ b,
                                               const float* __restrict__ vsrc,
                                               const float* __restrict__ vdst,
                                               __half* __restrict__ h1,
                                               float* __restrict__ as_o,
                                               float* __restrict__ ad_o) {
    __shared__ int sbuf[4][CHUNK];
    int lane = threadIdx.x & 63, wv = threadIdx.x >> 6;
    int half = lane >> 5, hl = lane & 31;
    int n = blockIdx.x * 4 + wv;
    if (n >= N_NODES) return;
    int rp = rowptr[n], re = rowptr[n + 1];
    float acc0 = 0.f, acc1 = 0.f;
    const __half* hp = h + hl * 2;
    for (int cb = rp; cb < re; cb += CHUNK) {
        int ce = min(cb + CHUNK, re);
        for (int e = cb + lane; e < ce; e += 64) sbuf[wv][e - cb] = colidx[e];
        int m = ce - cb;
        int npair = m >> 1;
#pragma unroll 2
        for (int i = 0; i < npair; i++) {
            int s = sbuf[wv][i * 2 + half];
            float2 hv = __half22float2(*(const __half2*)&hp[s * HID]);
            acc0 += hv.x; acc1 += hv.y;
        }
        if (m & 1) {
            int s = sbuf[wv][m - 1];
            float2 hv = __half22float2(*(const __half2*)&hp[s * HID]);
            if (half == 0) { acc0 += hv.x; acc1 += hv.y; }
        }
    }
    acc0 += __shfl_xor(acc0, 32);
    acc1 += __shfl_xor(acc1, 32);
    float dn = dinv[n];
    float2 bb = *(const float2*)&b[hl * 2];
    float v0 = fmaxf(acc0 * dn + bb.x, 0.f);
    float v1 = fmaxf(acc1 * dn + bb.y, 0.f);
    if (half == 0)
        *(__half2*)&h1[n * HID + hl * 2] = __floats2half2_rn(v0, v1);
    // attention dots: a_s[n][h] = h1[n] . vsrc[h]  (upper half zeroed to avoid double count)
    float msk = (half == 0) ? 1.f : 0.f;
#pragma unroll
    for (int hh = 0; hh < 4; hh++) {
        float2 vsp = *(const float2*)&vsrc[hh * 64 + hl * 2];
        float2 vdp = *(const float2*)&vdst[hh * 64 + hl * 2];
        float vs = msk * (v0 * vsp.x + v1 * vsp.y);
        float vd = msk * (v0 * vdp.x + v1 * vdp.y);
#pragma unroll
        for (int off = 16; off > 0; off >>= 1) {
            vs += __shfl_xor(vs, off);
            vd += __shfl_xor(vd, off);
        }
        if (lane == 0) {
            as_o[n * 4 + hh] = vs;
            ad_o[n * 4 + hh] = vd;
        }
    }
}

// ---------------------------------------------------------------- GAT aggregate over fp16 h1: u[n][h][k] = (sum_s w_h*h1[s][k]) / den_h
__global__ __launch_bounds__(256) void gat_agg(const __half* __restrict__ h1,
                                               const int* __restrict__ rowptr,
                                               const int* __restrict__ colidx,
                                               const float* __restrict__ a_s,
                                               const float* __restrict__ a_d,
                                               float* __restrict__ u) {
    __shared__ float wbuf[4][(CHUNK + 1) * 4];  // +1 pad slot for odd tails
    __shared__ int   sbuf[4][CHUNK + 1];
    int lane = threadIdx.x & 63, wv = threadIdx.x >> 6;
    int half = lane >> 5, hl = lane & 31;
    int n = blockIdx.x * 4 + wv;
    if (n >= N_NODES) return;
    int rp = rowptr[n], re = rowptr[n + 1];
    float4 ad4 = *(const float4*)&a_d[n * 4];

    // ---- phase A: distributed per-head max of a_s (leaky monotone: apply once after)
    float mx = -1e30f, my = -1e30f, mz = -1e30f, mw = -1e30f;
    for (int e = rp + lane; e < re; e += 64) {
        int s = colidx[e];
        float4 a = *(const float4*)&a_s[s * 4];
        mx = fmaxf(mx, a.x); my = fmaxf(my, a.y);
        mz = fmaxf(mz, a.z); mw = fmaxf(mw, a.w);
    }
#pragma unroll
    for (int off = 32; off > 0; off >>= 1) {
        mx = fmaxf(mx, __shfl_xor(mx, off));
        my = fmaxf(my, __shfl_xor(my, off));
        mz = fmaxf(mz, __shfl_xor(mz, off));
        mw = fmaxf(mw, __shfl_xor(mw, off));
    }
    mx += ad4.x; mx = fmaxf(mx, NEG_SLOPE * mx);
    my += ad4.y; my = fmaxf(my, NEG_SLOPE * my);
    mz += ad4.z; mz = fmaxf(mz, NEG_SLOPE * mz);
    mw += ad4.w; mw = fmaxf(mw, NEG_SLOPE * mw);

    // ---- phases B/C, chunked
    float dnx = 0.f, dny = 0.f, dnz = 0.f, dnw = 0.f;
    float a00 = 0.f, a01 = 0.f, a10 = 0.f, a11 = 0.f;
    float a20 = 0.f, a21 = 0.f, a30 = 0.f, a31 = 0.f;
    const __half* hp = h1 + hl * 2;
    for (int cb = rp; cb < re; cb += CHUNK) {
        int ce = min(cb + CHUNK, re);
        // phase B: distributed weight computation -> LDS
        for (int e = cb + lane; e < ce; e += 64) {
            int s = colidx[e];
            float4 a = *(const float4*)&a_s[s * 4];
            float vx = a.x + ad4.x; vx = fmaxf(vx, NEG_SLOPE * vx);
            float vy = a.y + ad4.y; vy = fmaxf(vy, NEG_SLOPE * vy);
            float vz = a.z + ad4.z; vz = fmaxf(vz, NEG_SLOPE * vz);
            float vw = a.w + ad4.w; vw = fmaxf(vw, NEG_SLOPE * vw);
            float wx = __expf(vx - mx), wy = __expf(vy - my);
            float wz = __expf(vz - mz), ww = __expf(vw - mw);
            dnx += wx; dny += wy; dnz += wz; dnw += ww;
            int idx = e - cb;
            *(float4*)&wbuf[wv][idx * 4] = make_float4(wx, wy, wz, ww);
            sbuf[wv][idx] = s;
        }
        int m = ce - cb;
        if ((m & 1) && lane == 0) {       // pad odd tail: zero-weight self edge
            sbuf[wv][m] = n;
            *(float4*)&wbuf[wv][m * 4] = make_float4(0.f, 0.f, 0.f, 0.f);
        }
        int npair = (m + 1) >> 1;
        // phase C: 2 edges per iteration (half-wave each), fp16 gather
#pragma unroll 2
        for (int i = 0; i < npair; i++) {
            int idx2 = i * 2 + half;
            int s = sbuf[wv][idx2];
            float4 w4 = *(const float4*)&wbuf[wv][idx2 * 4];
            float2 g = __half22float2(*(const __half2*)&hp[s * HID]);
            a00 += w4.x * g.x; a01 += w4.x * g.y;
            a10 += w4.y * g.x; a11 += w4.y * g.y;
            a20 += w4.z * g.x; a21 += w4.z * g.y;
            a30 += w4.w * g.x; a31 += w4.w * g.y;
        }
    }
    // combine the two half-wave edge subsets
    a00 += __shfl_xor(a00, 32); a01 += __shfl_xor(a01, 32);
    a10 += __shfl_xor(a10, 32); a11 += __shfl_xor(a11, 32);
    a20 += __shfl_xor(a20, 32); a21 += __shfl_xor(a21, 32);
    a30 += __shfl_xor(a30, 32); a31 += __shfl_xor(a31, 32);
    // reduce denominators across lanes
#pragma unroll
    for (int off = 32; off > 0; off >>= 1) {
        dnx += __shfl_xor(dnx, off);
        dny += __shfl_xor(dny, off);
        dnz += __shfl_xor(dnz, off);
        dnw += __shfl_xor(dnw, off);
    }
    if (half == 0) {
        float* up = u + n * 256 + hl * 2;
        *(float2*)&up[0]   = make_float2(a00 / dnx, a01 / dnx);
        *(float2*)&up[64]  = make_float2(a10 / dny, a11 / dny);
        *(float2*)&up[128] = make_float2(a20 / dnz, a21 / dnz);
        *(float2*)&up[192] = make_float2(a30 / dnw, a31 / dnw);
    }
}

// ---------------------------------------------------------------- gemm2b: h2 = relu(u @ blockdiag(W_gat) + b)
__global__ __launch_bounds__(256) void gemm2b(const float* __restrict__ u,
                                              const float* __restrict__ W,
                                              const float* __restrict__ b,
                                              float* __restrict__ h2) {
    __shared__ float Wl[HID * 256];       // 64 KB
    int t = threadIdx.x, lane = t & 63, hd = t >> 6;
    for (int i = t; i < HID * 256; i += 256) Wl[i] = W[i];
    __syncthreads();
    int r0 = blockIdx.x * 8;
    float ureg[8];
#pragma unroll
    for (int r = 0; r < 8; r++)
        ureg[r] = (r0 + r < N_NODES) ? u[(r0 + r) * 256 + hd * 64 + lane] : 0.f;
    float acc[8];
#pragma unroll
    for (int r = 0; r < 8; r++) acc[r] = 0.f;
#pragma unroll 16
    for (int k = 0; k < 64; k++) {
        float w = Wl[k * 256 + hd * 64 + lane];
#pragma unroll
        for (int r = 0; r < 8; r++) {
            float s = __int_as_float(__builtin_amdgcn_readlane(__float_as_int(ureg[r]), k));
            acc[r] += s * w;
        }
    }
    float bb = b[hd * 64 + lane];
#pragma unroll
    for (int r = 0; r < 8; r++)
        if (r0 + r < N_NODES)
            h2[(r0 + r) * 256 + hd * 64 + lane] = fmaxf(acc[r] + bb, 0.f);
}

// ---------------------------------------------------------------- GEMM3: out = h2 @ W_fc + b_fc
__global__ __launch_bounds__(256) void gemm3(const float* __restrict__ h2,
                                             const float* __restrict__ W,
                                             const float* __restrict__ b,
                                             float* __restrict__ out) {
    __shared__ float Wl[256 * D_OUT];     // 32 KB
    int t = threadIdx.x;
    for (int i = t; i < 256 * D_OUT; i += 256) Wl[i] = W[i];
    __syncthreads();
    int c = t & 31, rw = t >> 5;
    int r0 = blockIdx.x * 32;
#pragma unroll
    for (int rr = 0; rr < 4; rr++) {
        int r = r0 + rr * 8 + rw;
        if (r >= N_NODES) break;
        const float4* hr4 = (const float4*)(h2 + r * 256);
        float acc = b[c];
#pragma unroll 8
        for (int k4 = 0; k4 < 64; k4++) {
            float4 hv = hr4[k4];
            int k = k4 * 4;
            acc += hv.x * Wl[(k+0)*D_OUT + c] + hv.y * Wl[(k+1)*D_OUT + c]
                 + hv.z * Wl[(k+2)*D_OUT + c] + hv.w * Wl[(k+3)*D_OUT + c];
        }
        out[r * D_OUT + c] = acc;
    }
}

// ---------------------------------------------------------------- launch
extern "C" void kernel_launch(void* const* d_in, const int* in_sizes, int n_in,
                              void* d_out, int out_size, void* d_ws, size_t ws_size,
                              hipStream_t stream) {
    const float* x      = (const float*)d_in[0];
    const int*   edge   = (const int*)  d_in[1];
    const float* W_gcn  = (const float*)d_in[2];
    const float* b_gcn  = (const float*)d_in[3];
    const float* W_gat  = (const float*)d_in[4];
    const float* att_s  = (const float*)d_in[5];
    const float* att_d  = (const float*)d_in[6];
    const float* b_gat  = (const float*)d_in[7];
    const float* W_fc   = (const float*)d_in[8];
    const float* b_fc   = (const float*)d_in[9];
    float* out = (float*)d_out;

    char* p = (char*)d_ws;
    auto alloc = [&](size_t bytes) {
        char* q = p;
        p += (bytes + 255) & ~(size_t)255;
        return q;
    };
    __half* h     = (__half*)alloc((size_t)N_NODES * HID * 2);
    __half* h1    = (__half*)alloc((size_t)N_NODES * HID * 2);
    float* u      = (float*)alloc((size_t)N_NODES * 256 * 4);
    float* h2     = (float*)alloc((size_t)N_NODES * 256 * 4);
    float* as_a   = (float*)alloc((size_t)N_NODES * 4 * 4);
    float* ad_a   = (float*)alloc((size_t)N_NODES * 4 * 4);
    float* dinv   = (float*)alloc((size_t)N_NODES * 4);
    int*   cnt    = (int*)  alloc((size_t)N_NODES * 4);
    int*   rowptr = (int*)  alloc((size_t)(N_NODES + 1) * 4);
    int*   colidx = (int*)  alloc((size_t)(N_EDGES + N_NODES) * 4);
    int*   eoff   = (int*)  alloc((size_t)N_EDGES * 4);
    int*   bsum   = (int*)  alloc((size_t)NB * 4);
    int*   boff   = (int*)  alloc((size_t)NB * 4);
    float* vsrc   = (float*)alloc((size_t)HEADS * HID * 4);
    float* vdst   = (float*)alloc((size_t)HEADS * HID * 4);

    // CSR build (atomic-free fill)
    init_cnt  <<<(N_NODES + 255) / 256, 256, 0, stream>>>(cnt);
    count_k   <<<(N_EDGES + 255) / 256, 256, 0, stream>>>(edge, cnt, eoff);
    blockred_k<<<NB, 256, 0, stream>>>(cnt, bsum);
    bscan_k   <<<1, 256, 0, stream>>>(bsum, boff, rowptr);
    scatter_k <<<NB, 256, 0, stream>>>(cnt, boff, rowptr, dinv, colidx);
    fill2_k   <<<(N_EDGES + 255) / 256, 256, 0, stream>>>(edge, eoff, rowptr, colidx);

    // attention projection vectors
    attvec_k<<<1, 256, 0, stream>>>(W_gat, att_s, att_d, vsrc, vdst);

    // GCN
    gemm1   <<<(N_NODES + 31) / 32, 256, 0, stream>>>(x, W_gcn, dinv, h);
    gcn_agg <<<(N_NODES + 3) / 4, 256, 0, stream>>>(h, rowptr, colidx, dinv, b_gcn,
                                                    vsrc, vdst, h1, as_a, ad_a);

    // GAT (gathers fp16 h1)
    gat_agg <<<(N_NODES + 3) / 4, 256, 0, stream>>>(h1, rowptr, colidx, as_a, ad_a, u);
    gemm2b  <<<(N_NODES + 7) / 8, 256, 0, stream>>>(u, W_gat, b_gat, h2);

    // FC
    gemm3   <<<(N_NODES + 31) / 32, 256, 0, stream>>>(h2, W_fc, b_fc, out);
}

// Round 6
// 348.256 us; speedup vs baseline: 2.8039x; 1.3143x over previous
//
#include <hip/hip_runtime.h>
#include <hip/hip_bf16.h>
#include <hip/hip_fp16.h>
#include <math.h>

#define N_NODES 50000
#define N_EDGES 1600000
#define D_IN    32
#define HID     64
#define HEADS   4
#define D_OUT   32
#define NEG_SLOPE 0.2f
#define NB 196   // ceil(N_NODES/256)
#define CHUNK 128
#define NTILES 3125   // N_NODES / 16, exact

typedef _Float16 half8 __attribute__((ext_vector_type(8)));
typedef float    f32x4 __attribute__((ext_vector_type(4)));

// ---------------------------------------------------------------- CSR build
__global__ __launch_bounds__(256) void init_cnt(int* __restrict__ cnt) {
    int i = blockIdx.x * 256 + threadIdx.x;
    if (i < N_NODES) cnt[i] = 1;          // slot 0 reserved for self-loop
}

__global__ __launch_bounds__(256) void count_k(const int* __restrict__ edge,
                                               int* __restrict__ cnt,
                                               int* __restrict__ eoff) {
    int i = blockIdx.x * 256 + threadIdx.x;
    if (i < N_EDGES) eoff[i] = atomicAdd(&cnt[edge[N_EDGES + i]], 1);
}

__global__ __launch_bounds__(256) void blockred_k(const int* __restrict__ cnt,
                                                  int* __restrict__ bsum) {
    int t = threadIdx.x;
    int i = blockIdx.x * 256 + t;
    int v = (i < N_NODES) ? cnt[i] : 0;
#pragma unroll
    for (int off = 32; off; off >>= 1) v += __shfl_xor(v, off);
    __shared__ int ws[4];
    if ((t & 63) == 0) ws[t >> 6] = v;
    __syncthreads();
    if (t == 0) bsum[blockIdx.x] = ws[0] + ws[1] + ws[2] + ws[3];
}

__global__ __launch_bounds__(256) void bscan_k(const int* __restrict__ bsum,
                                               int* __restrict__ boff,
                                               int* __restrict__ rowptr) {
    int t = threadIdx.x, lane = t & 63, wv = t >> 6;
    int v = (t < NB) ? bsum[t] : 0;
    int inc = v;
#pragma unroll
    for (int d = 1; d < 64; d <<= 1) {
        int u = __shfl_up(inc, d);
        if (lane >= d) inc += u;
    }
    __shared__ int ws[4];
    if (lane == 63) ws[wv] = inc;
    __syncthreads();
    int add = 0;
#pragma unroll
    for (int j = 0; j < 4; j++) if (j < wv) add += ws[j];
    inc += add;
    if (t < NB) boff[t] = inc - v;
    if (t == NB - 1) rowptr[N_NODES] = inc;
}

__global__ __launch_bounds__(256) void scatter_k(const int* __restrict__ cnt,
                                                 const int* __restrict__ boff,
                                                 int* __restrict__ rowptr,
                                                 float* __restrict__ dinv,
                                                 int* __restrict__ colidx) {
    int t = threadIdx.x, lane = t & 63, wv = t >> 6;
    int i = blockIdx.x * 256 + t;
    int v = (i < N_NODES) ? cnt[i] : 0;
    int inc = v;
#pragma unroll
    for (int d = 1; d < 64; d <<= 1) {
        int u = __shfl_up(inc, d);
        if (lane >= d) inc += u;
    }
    __shared__ int ws[4];
    if (lane == 63) ws[wv] = inc;
    __syncthreads();
    int add = 0;
#pragma unroll
    for (int j = 0; j < 4; j++) if (j < wv) add += ws[j];
    int exc = boff[blockIdx.x] + inc + add - v;
    if (i < N_NODES) {
        rowptr[i] = exc;
        dinv[i]   = rsqrtf((float)v);
        colidx[exc] = i;                  // self-loop at slot 0
    }
}

__global__ __launch_bounds__(256) void fill2_k(const int* __restrict__ edge,
                                               const int* __restrict__ eoff,
                                               const int* __restrict__ rowptr,
                                               int* __restrict__ colidx) {
    int i = blockIdx.x * 256 + threadIdx.x;
    if (i < N_EDGES) {
        int s = edge[i], d = edge[N_EDGES + i];
        colidx[rowptr[d] + eoff[i]] = s;
    }
}

// ---------------------------------------------------------------- attention projection vectors
__global__ __launch_bounds__(256) void attvec_k(const float* __restrict__ W,
                                                const float* __restrict__ att_s,
                                                const float* __restrict__ att_d,
                                                float* __restrict__ vsrc,
                                                float* __restrict__ vdst) {
    int t = threadIdx.x;
    int h = t >> 6, k = t & 63;
    float s_ = 0.f, d_ = 0.f;
#pragma unroll 8
    for (int c = 0; c < 64; c++) {
        float w = W[k * 256 + h * 64 + c];
        s_ += w * att_s[h * 64 + c];
        d_ += w * att_d[h * 64 + c];
    }
    vsrc[h * 64 + k] = s_;
    vdst[h * 64 + k] = d_;
}

// ---------------------------------------------------------------- GEMM1: h = fp16( dinv .* (x @ W_gcn) )
__global__ __launch_bounds__(256) void gemm1(const float* __restrict__ x,
                                             const float* __restrict__ W,
                                             const float* __restrict__ dinv,
                                             __half* __restrict__ h) {
    __shared__ float Wl[D_IN * HID];      // 8 KB
    int t = threadIdx.x;
    for (int i = t; i < D_IN * HID; i += 256) Wl[i] = W[i];
    __syncthreads();
    int c = t & 63, rw = t >> 6;
    int r0 = blockIdx.x * 32;
#pragma unroll
    for (int rr = 0; rr < 8; rr++) {
        int r = r0 + rr * 4 + rw;
        if (r >= N_NODES) break;
        const float4* xr4 = (const float4*)(x + r * D_IN);
        float acc = 0.f;
#pragma unroll
        for (int k4 = 0; k4 < D_IN / 4; k4++) {
            float4 xv = xr4[k4];
            int k = k4 * 4;
            acc += xv.x * Wl[(k+0)*HID + c] + xv.y * Wl[(k+1)*HID + c]
                 + xv.z * Wl[(k+2)*HID + c] + xv.w * Wl[(k+3)*HID + c];
        }
        h[r * HID + c] = __float2half(acc * dinv[r]);
    }
}

// ---------------------------------------------------------------- GCN aggregate -> h1 fp16 (relu), fused attention dots
__global__ __launch_bounds__(256) void gcn_agg(const __half* __restrict__ h,
                                               const int* __restrict__ rowptr,
                                               const int* __restrict__ colidx,
                                               const float* __restrict__ dinv,
                                               const float* __restrict__ b,
                                               const float* __restrict__ vsrc,
                                               const float* __restrict__ vdst,
                                               __half* __restrict__ h1,
                                               float* __restrict__ as_o,
                                               float* __restrict__ ad_o) {
    __shared__ int sbuf[4][CHUNK];
    int lane = threadIdx.x & 63, wv = threadIdx.x >> 6;
    int half = lane >> 5, hl = lane & 31;
    int n = blockIdx.x * 4 + wv;
    if (n >= N_NODES) return;
    int rp = rowptr[n], re = rowptr[n + 1];
    float acc0 = 0.f, acc1 = 0.f;
    const __half* hp = h + hl * 2;
    for (int cb = rp; cb < re; cb += CHUNK) {
        int ce = min(cb + CHUNK, re);
        for (int e = cb + lane; e < ce; e += 64) sbuf[wv][e - cb] = colidx[e];
        int m = ce - cb;
        int npair = m >> 1;
#pragma unroll 2
        for (int i = 0; i < npair; i++) {
            int s = sbuf[wv][i * 2 + half];
            float2 hv = __half22float2(*(const __half2*)&hp[s * HID]);
            acc0 += hv.x; acc1 += hv.y;
        }
        if (m & 1) {
            int s = sbuf[wv][m - 1];
            float2 hv = __half22float2(*(const __half2*)&hp[s * HID]);
            if (half == 0) { acc0 += hv.x; acc1 += hv.y; }
        }
    }
    acc0 += __shfl_xor(acc0, 32);
    acc1 += __shfl_xor(acc1, 32);
    float dn = dinv[n];
    float2 bb = *(const float2*)&b[hl * 2];
    float v0 = fmaxf(acc0 * dn + bb.x, 0.f);
    float v1 = fmaxf(acc1 * dn + bb.y, 0.f);
    if (half == 0)
        *(__half2*)&h1[n * HID + hl * 2] = __floats2half2_rn(v0, v1);
    float msk = (half == 0) ? 1.f : 0.f;
#pragma unroll
    for (int hh = 0; hh < 4; hh++) {
        float2 vsp = *(const float2*)&vsrc[hh * 64 + hl * 2];
        float2 vdp = *(const float2*)&vdst[hh * 64 + hl * 2];
        float vs = msk * (v0 * vsp.x + v1 * vsp.y);
        float vd = msk * (v0 * vdp.x + v1 * vdp.y);
#pragma unroll
        for (int off = 16; off > 0; off >>= 1) {
            vs += __shfl_xor(vs, off);
            vd += __shfl_xor(vd, off);
        }
        if (lane == 0) {
            as_o[n * 4 + hh] = vs;
            ad_o[n * 4 + hh] = vd;
        }
    }
}

// ---------------------------------------------------------------- GAT aggregate over fp16 h1 -> u fp32 (pre-divided)
__global__ __launch_bounds__(256) void gat_agg(const __half* __restrict__ h1,
                                               const int* __restrict__ rowptr,
                                               const int* __restrict__ colidx,
                                               const float* __restrict__ a_s,
                                               const float* __restrict__ a_d,
                                               float* __restrict__ u) {
    __shared__ float wbuf[4][(CHUNK + 1) * 4];
    __shared__ int   sbuf[4][CHUNK + 1];
    int lane = threadIdx.x & 63, wv = threadIdx.x >> 6;
    int half = lane >> 5, hl = lane & 31;
    int n = blockIdx.x * 4 + wv;
    if (n >= N_NODES) return;
    int rp = rowptr[n], re = rowptr[n + 1];
    float4 ad4 = *(const float4*)&a_d[n * 4];

    float mx = -1e30f, my = -1e30f, mz = -1e30f, mw = -1e30f;
    for (int e = rp + lane; e < re; e += 64) {
        int s = colidx[e];
        float4 a = *(const float4*)&a_s[s * 4];
        mx = fmaxf(mx, a.x); my = fmaxf(my, a.y);
        mz = fmaxf(mz, a.z); mw = fmaxf(mw, a.w);
    }
#pragma unroll
    for (int off = 32; off > 0; off >>= 1) {
        mx = fmaxf(mx, __shfl_xor(mx, off));
        my = fmaxf(my, __shfl_xor(my, off));
        mz = fmaxf(mz, __shfl_xor(mz, off));
        mw = fmaxf(mw, __shfl_xor(mw, off));
    }
    mx += ad4.x; mx = fmaxf(mx, NEG_SLOPE * mx);
    my += ad4.y; my = fmaxf(my, NEG_SLOPE * my);
    mz += ad4.z; mz = fmaxf(mz, NEG_SLOPE * mz);
    mw += ad4.w; mw = fmaxf(mw, NEG_SLOPE * mw);

    float dnx = 0.f, dny = 0.f, dnz = 0.f, dnw = 0.f;
    float a00 = 0.f, a01 = 0.f, a10 = 0.f, a11 = 0.f;
    float a20 = 0.f, a21 = 0.f, a30 = 0.f, a31 = 0.f;
    const __half* hp = h1 + hl * 2;
    for (int cb = rp; cb < re; cb += CHUNK) {
        int ce = min(cb + CHUNK, re);
        for (int e = cb + lane; e < ce; e += 64) {
            int s = colidx[e];
            float4 a = *(const float4*)&a_s[s * 4];
            float vx = a.x + ad4.x; vx = fmaxf(vx, NEG_SLOPE * vx);
            float vy = a.y + ad4.y; vy = fmaxf(vy, NEG_SLOPE * vy);
            float vz = a.z + ad4.z; vz = fmaxf(vz, NEG_SLOPE * vz);
            float vw = a.w + ad4.w; vw = fmaxf(vw, NEG_SLOPE * vw);
            float wx = __expf(vx - mx), wy = __expf(vy - my);
            float wz = __expf(vz - mz), ww = __expf(vw - mw);
            dnx += wx; dny += wy; dnz += wz; dnw += ww;
            int idx = e - cb;
            *(float4*)&wbuf[wv][idx * 4] = make_float4(wx, wy, wz, ww);
            sbuf[wv][idx] = s;
        }
        int m = ce - cb;
        if ((m & 1) && lane == 0) {
            sbuf[wv][m] = n;
            *(float4*)&wbuf[wv][m * 4] = make_float4(0.f, 0.f, 0.f, 0.f);
        }
        int npair = (m + 1) >> 1;
#pragma unroll 2
        for (int i = 0; i < npair; i++) {
            int idx2 = i * 2 + half;
            int s = sbuf[wv][idx2];
            float4 w4 = *(const float4*)&wbuf[wv][idx2 * 4];
            float2 g = __half22float2(*(const __half2*)&hp[s * HID]);
            a00 += w4.x * g.x; a01 += w4.x * g.y;
            a10 += w4.y * g.x; a11 += w4.y * g.y;
            a20 += w4.z * g.x; a21 += w4.z * g.y;
            a30 += w4.w * g.x; a31 += w4.w * g.y;
        }
    }
    a00 += __shfl_xor(a00, 32); a01 += __shfl_xor(a01, 32);
    a10 += __shfl_xor(a10, 32); a11 += __shfl_xor(a11, 32);
    a20 += __shfl_xor(a20, 32); a21 += __shfl_xor(a21, 32);
    a30 += __shfl_xor(a30, 32); a31 += __shfl_xor(a31, 32);
#pragma unroll
    for (int off = 32; off > 0; off >>= 1) {
        dnx += __shfl_xor(dnx, off);
        dny += __shfl_xor(dny, off);
        dnz += __shfl_xor(dnz, off);
        dnw += __shfl_xor(dnw, off);
    }
    if (half == 0) {
        float* up = u + n * 256 + hl * 2;
        *(float2*)&up[0]   = make_float2(a00 / dnx, a01 / dnx);
        *(float2*)&up[64]  = make_float2(a10 / dny, a11 / dny);
        *(float2*)&up[128] = make_float2(a20 / dnz, a21 / dnz);
        *(float2*)&up[192] = make_float2(a30 / dnw, a31 / dnw);
    }
}

// ---------------------------------------------------------------- gemm2b (MFMA): h2 = relu(u @ blockdiag(W_gat) + b)
// wave = head hd. A: u rows (fp32 -> fp16 on load). B: W_gat fp16 frags, loop-invariant.
// Layouts: A[m=lane&15][k=quad*8+j]; B[k=quad*8+j][n=lane&15]; D col=lane&15,row=quad*4+reg.
__global__ __launch_bounds__(256) void gemm2b(const float* __restrict__ u,
                                              const float* __restrict__ W,
                                              const float* __restrict__ b,
                                              float* __restrict__ h2) {
    int lane = threadIdx.x & 63, hd = threadIdx.x >> 6;
    int quad = lane >> 4, l16 = lane & 15;
    // preload B fragments: Bf[nt][kc], element j = W[(kc*32+quad*8+j)*256 + hd*64 + nt*16 + l16]
    half8 Bf[4][2];
#pragma unroll
    for (int nt = 0; nt < 4; nt++)
#pragma unroll
        for (int kc = 0; kc < 2; kc++) {
            const float* wp = W + (kc * 32 + quad * 8) * 256 + hd * 64 + nt * 16 + l16;
#pragma unroll
            for (int j = 0; j < 8; j++)
                Bf[nt][kc][j] = (_Float16)wp[j * 256];
        }
    float bb[4];
#pragma unroll
    for (int nt = 0; nt < 4; nt++) bb[nt] = b[hd * 64 + nt * 16 + l16];

    int rt0 = blockIdx.x * 5;             // 625 blocks x 5 tiles = 3125 exact
#pragma unroll
    for (int i = 0; i < 5; i++) {
        int rt = rt0 + i;
        const float* up = u + ((size_t)(rt * 16 + l16)) * 256 + hd * 64 + quad * 8;
        float4 a0 = *(const float4*)up;
        float4 a1 = *(const float4*)(up + 4);
        float4 a2 = *(const float4*)(up + 32);
        float4 a3 = *(const float4*)(up + 36);
        half8 A0, A1;
        A0[0]=(_Float16)a0.x; A0[1]=(_Float16)a0.y; A0[2]=(_Float16)a0.z; A0[3]=(_Float16)a0.w;
        A0[4]=(_Float16)a1.x; A0[5]=(_Float16)a1.y; A0[6]=(_Float16)a1.z; A0[7]=(_Float16)a1.w;
        A1[0]=(_Float16)a2.x; A1[1]=(_Float16)a2.y; A1[2]=(_Float16)a2.z; A1[3]=(_Float16)a2.w;
        A1[4]=(_Float16)a3.x; A1[5]=(_Float16)a3.y; A1[6]=(_Float16)a3.z; A1[7]=(_Float16)a3.w;
        f32x4 acc[4];
#pragma unroll
        for (int nt = 0; nt < 4; nt++) {
            acc[nt] = (f32x4){0.f, 0.f, 0.f, 0.f};
            acc[nt] = __builtin_amdgcn_mfma_f32_16x16x32_f16(A0, Bf[nt][0], acc[nt], 0, 0, 0);
            acc[nt] = __builtin_amdgcn_mfma_f32_16x16x32_f16(A1, Bf[nt][1], acc[nt], 0, 0, 0);
        }
#pragma unroll
        for (int nt = 0; nt < 4; nt++) {
            int col = hd * 64 + nt * 16 + l16;
#pragma unroll
            for (int reg = 0; reg < 4; reg++) {
                int row = rt * 16 + quad * 4 + reg;
                h2[(size_t)row * 256 + col] = fmaxf(acc[nt][reg] + bb[nt], 0.f);
            }
        }
    }
}

// ---------------------------------------------------------------- gemm3 (MFMA): out = h2 @ W_fc + b_fc
__global__ __launch_bounds__(256) void gemm3(const float* __restrict__ h2,
                                             const float* __restrict__ W,
                                             const float* __restrict__ b,
                                             float* __restrict__ out) {
    int lane = threadIdx.x & 63, wv = threadIdx.x >> 6;
    int quad = lane >> 4, l16 = lane & 15;
    // preload B fragments: Bf[nt][kc], element j = W[(kc*32+quad*8+j)*32 + nt*16 + l16]
    half8 Bf[2][8];
#pragma unroll
    for (int nt = 0; nt < 2; nt++)
#pragma unroll
        for (int kc = 0; kc < 8; kc++) {
            const float* wp = W + (kc * 32 + quad * 8) * 32 + nt * 16 + l16;
#pragma unroll
            for (int j = 0; j < 8; j++)
                Bf[nt][kc][j] = (_Float16)wp[j * 32];
        }
    float bb0 = b[l16], bb1 = b[16 + l16];

    for (int tile = blockIdx.x * 4 + wv; tile < NTILES; tile += gridDim.x * 4) {
        const float* hp = h2 + (size_t)(tile * 16 + l16) * 256 + quad * 8;
        f32x4 acc0 = {0.f, 0.f, 0.f, 0.f};
        f32x4 acc1 = {0.f, 0.f, 0.f, 0.f};
#pragma unroll
        for (int kc = 0; kc < 8; kc++) {
            float4 a0 = *(const float4*)(hp + kc * 32);
            float4 a1 = *(const float4*)(hp + kc * 32 + 4);
            half8 A;
            A[0]=(_Float16)a0.x; A[1]=(_Float16)a0.y; A[2]=(_Float16)a0.z; A[3]=(_Float16)a0.w;
            A[4]=(_Float16)a1.x; A[5]=(_Float16)a1.y; A[6]=(_Float16)a1.z; A[7]=(_Float16)a1.w;
            acc0 = __builtin_amdgcn_mfma_f32_16x16x32_f16(A, Bf[0][kc], acc0, 0, 0, 0);
            acc1 = __builtin_amdgcn_mfma_f32_16x16x32_f16(A, Bf[1][kc], acc1, 0, 0, 0);
        }
#pragma unroll
        for (int reg = 0; reg < 4; reg++) {
            int row = tile * 16 + quad * 4 + reg;
            out[row * 32 + l16]      = acc0[reg] + bb0;
            out[row * 32 + 16 + l16] = acc1[reg] + bb1;
        }
    }
}

// ---------------------------------------------------------------- launch
extern "C" void kernel_launch(void* const* d_in, const int* in_sizes, int n_in,
                              void* d_out, int out_size, void* d_ws, size_t ws_size,
                              hipStream_t stream) {
    const float* x      = (const float*)d_in[0];
    const int*   edge   = (const int*)  d_in[1];
    const float* W_gcn  = (const float*)d_in[2];
    const float* b_gcn  = (const float*)d_in[3];
    const float* W_gat  = (const float*)d_in[4];
    const float* att_s  = (const float*)d_in[5];
    const float* att_d  = (const float*)d_in[6];
    const float* b_gat  = (const float*)d_in[7];
    const float* W_fc   = (const float*)d_in[8];
    const float* b_fc   = (const float*)d_in[9];
    float* out = (float*)d_out;

    char* p = (char*)d_ws;
    auto alloc = [&](size_t bytes) {
        char* q = p;
        p += (bytes + 255) & ~(size_t)255;
        return q;
    };
    __half* h     = (__half*)alloc((size_t)N_NODES * HID * 2);
    __half* h1    = (__half*)alloc((size_t)N_NODES * HID * 2);
    float* u      = (float*)alloc((size_t)N_NODES * 256 * 4);
    float* h2     = (float*)alloc((size_t)N_NODES * 256 * 4);
    float* as_a   = (float*)alloc((size_t)N_NODES * 4 * 4);
    float* ad_a   = (float*)alloc((size_t)N_NODES * 4 * 4);
    float* dinv   = (float*)alloc((size_t)N_NODES * 4);
    int*   cnt    = (int*)  alloc((size_t)N_NODES * 4);
    int*   rowptr = (int*)  alloc((size_t)(N_NODES + 1) * 4);
    int*   colidx = (int*)  alloc((size_t)(N_EDGES + N_NODES) * 4);
    int*   eoff   = (int*)  alloc((size_t)N_EDGES * 4);
    int*   bsum   = (int*)  alloc((size_t)NB * 4);
    int*   boff   = (int*)  alloc((size_t)NB * 4);
    float* vsrc   = (float*)alloc((size_t)HEADS * HID * 4);
    float* vdst   = (float*)alloc((size_t)HEADS * HID * 4);

    // CSR build (atomic-free fill)
    init_cnt  <<<(N_NODES + 255) / 256, 256, 0, stream>>>(cnt);
    count_k   <<<(N_EDGES + 255) / 256, 256, 0, stream>>>(edge, cnt, eoff);
    blockred_k<<<NB, 256, 0, stream>>>(cnt, bsum);
    bscan_k   <<<1, 256, 0, stream>>>(bsum, boff, rowptr);
    scatter_k <<<NB, 256, 0, stream>>>(cnt, boff, rowptr, dinv, colidx);
    fill2_k   <<<(N_EDGES + 255) / 256, 256, 0, stream>>>(edge, eoff, rowptr, colidx);

    // attention projection vectors
    attvec_k<<<1, 256, 0, stream>>>(W_gat, att_s, att_d, vsrc, vdst);

    // GCN
    gemm1   <<<(N_NODES + 31) / 32, 256, 0, stream>>>(x, W_gcn, dinv, h);
    gcn_agg <<<(N_NODES + 3) / 4, 256, 0, stream>>>(h, rowptr, colidx, dinv, b_gcn,
                                                    vsrc, vdst, h1, as_a, ad_a);

    // GAT
    gat_agg <<<(N_NODES + 3) / 4, 256, 0, stream>>>(h1, rowptr, colidx, as_a, ad_a, u);
    gemm2b  <<<625, 256, 0, stream>>>(u, W_gat, b_gat, h2);

    // FC
    gemm3   <<<256, 256, 0, stream>>>(h2, W_fc, b_fc, out);
}

// Round 7
// 336.890 us; speedup vs baseline: 2.8985x; 1.0337x over previous
//
#include <hip/hip_runtime.h>
#include <hip/hip_bf16.h>
#include <hip/hip_fp16.h>
#include <math.h>

#define N_NODES 50000
#define N_EDGES 1600000
#define D_IN    32
#define HID     64
#define HEADS   4
#define D_OUT   32
#define NEG_SLOPE 0.2f
#define NB 196   // ceil(N_NODES/256)
#define CHUNK 128
#define NTILES 3125   // N_NODES / 16, exact
#define NXCD 8

typedef _Float16 half8 __attribute__((ext_vector_type(8)));
typedef float    f32x4 __attribute__((ext_vector_type(4)));

// ---------------------------------------------------------------- CSR build (XCD-privatized counters)
// count + claim per-edge slot in the block-label-private counter array.
// Label x = blockIdx.x & 7 tracks the XCD under round-robin dispatch; correctness
// does NOT depend on the mapping (G16) -- only atomic line locality does.
__global__ __launch_bounds__(256) void count_k(const int* __restrict__ edge,
                                               int* __restrict__ cnt8,
                                               unsigned short* __restrict__ eoff) {
    int i = blockIdx.x * 256 + threadIdx.x;
    int x = blockIdx.x & (NXCD - 1);
    if (i < N_EDGES) {
        int d = edge[N_EDGES + i];
        eoff[i] = (unsigned short)atomicAdd(&cnt8[x * N_NODES + d], 1);
    }
}

__global__ __launch_bounds__(256) void blockred_k(const int* __restrict__ cnt8,
                                                  int* __restrict__ bsum) {
    int t = threadIdx.x;
    int i = blockIdx.x * 256 + t;
    int v = 0;
    if (i < N_NODES) {
        v = 1;                            // self-loop
#pragma unroll
        for (int x = 0; x < NXCD; x++) v += cnt8[x * N_NODES + i];
    }
#pragma unroll
    for (int off = 32; off; off >>= 1) v += __shfl_xor(v, off);
    __shared__ int ws[4];
    if ((t & 63) == 0) ws[t >> 6] = v;
    __syncthreads();
    if (t == 0) bsum[blockIdx.x] = ws[0] + ws[1] + ws[2] + ws[3];
}

__global__ __launch_bounds__(256) void bscan_k(const int* __restrict__ bsum,
                                               int* __restrict__ boff,
                                               int* __restrict__ rowptr) {
    int t = threadIdx.x, lane = t & 63, wv = t >> 6;
    int v = (t < NB) ? bsum[t] : 0;
    int inc = v;
#pragma unroll
    for (int d = 1; d < 64; d <<= 1) {
        int u = __shfl_up(inc, d);
        if (lane >= d) inc += u;
    }
    __shared__ int ws[4];
    if (lane == 63) ws[wv] = inc;
    __syncthreads();
    int add = 0;
#pragma unroll
    for (int j = 0; j < 4; j++) if (j < wv) add += ws[j];
    inc += add;
    if (t < NB) boff[t] = inc - v;
    if (t == NB - 1) rowptr[N_NODES] = inc;
}

__global__ __launch_bounds__(256) void scatter_k(const int* __restrict__ cnt8,
                                                 const int* __restrict__ boff,
                                                 int* __restrict__ rowptr,
                                                 float* __restrict__ dinv,
                                                 int* __restrict__ colidx,
                                                 int* __restrict__ xbase) {
    int t = threadIdx.x, lane = t & 63, wv = t >> 6;
    int i = blockIdx.x * 256 + t;
    int c8[NXCD];
    int deg = 0;
    if (i < N_NODES) {
        deg = 1;
#pragma unroll
        for (int x = 0; x < NXCD; x++) { c8[x] = cnt8[x * N_NODES + i]; deg += c8[x]; }
    }
    int inc = deg;
#pragma unroll
    for (int d = 1; d < 64; d <<= 1) {
        int u = __shfl_up(inc, d);
        if (lane >= d) inc += u;
    }
    __shared__ int ws[4];
    if (lane == 63) ws[wv] = inc;
    __syncthreads();
    int add = 0;
#pragma unroll
    for (int j = 0; j < 4; j++) if (j < wv) add += ws[j];
    int exc = boff[blockIdx.x] + inc + add - deg;
    if (i < N_NODES) {
        rowptr[i] = exc;
        dinv[i]   = rsqrtf((float)deg);
        colidx[exc] = i;                  // self-loop at slot 0
        int run = exc + 1;
#pragma unroll
        for (int x = 0; x < NXCD; x++) { xbase[x * N_NODES + i] = run; run += c8[x]; }
    }
}

__global__ __launch_bounds__(256) void fill2_k(const int* __restrict__ edge,
                                               const unsigned short* __restrict__ eoff,
                                               const int* __restrict__ xbase,
                                               int* __restrict__ colidx) {
    int i = blockIdx.x * 256 + threadIdx.x;
    int x = blockIdx.x & (NXCD - 1);      // same grid geometry as count_k -> same label
    if (i < N_EDGES) {
        int s = edge[i], d = edge[N_EDGES + i];
        colidx[xbase[x * N_NODES + d] + (int)eoff[i]] = s;
    }
}

// ---------------------------------------------------------------- attention projection vectors
__global__ __launch_bounds__(256) void attvec_k(const float* __restrict__ W,
                                                const float* __restrict__ att_s,
                                                const float* __restrict__ att_d,
                                                float* __restrict__ vsrc,
                                                float* __restrict__ vdst) {
    int t = threadIdx.x;
    int h = t >> 6, k = t & 63;
    float s_ = 0.f, d_ = 0.f;
#pragma unroll 8
    for (int c = 0; c < 64; c++) {
        float w = W[k * 256 + h * 64 + c];
        s_ += w * att_s[h * 64 + c];
        d_ += w * att_d[h * 64 + c];
    }
    vsrc[h * 64 + k] = s_;
    vdst[h * 64 + k] = d_;
}

// ---------------------------------------------------------------- GEMM1: h = fp16( dinv .* (x @ W_gcn) )
__global__ __launch_bounds__(256) void gemm1(const float* __restrict__ x,
                                             const float* __restrict__ W,
                                             const float* __restrict__ dinv,
                                             __half* __restrict__ h) {
    __shared__ float Wl[D_IN * HID];      // 8 KB
    int t = threadIdx.x;
    for (int i = t; i < D_IN * HID; i += 256) Wl[i] = W[i];
    __syncthreads();
    int c = t & 63, rw = t >> 6;
    int r0 = blockIdx.x * 32;
#pragma unroll
    for (int rr = 0; rr < 8; rr++) {
        int r = r0 + rr * 4 + rw;
        if (r >= N_NODES) break;
        const float4* xr4 = (const float4*)(x + r * D_IN);
        float acc = 0.f;
#pragma unroll
        for (int k4 = 0; k4 < D_IN / 4; k4++) {
            float4 xv = xr4[k4];
            int k = k4 * 4;
            acc += xv.x * Wl[(k+0)*HID + c] + xv.y * Wl[(k+1)*HID + c]
                 + xv.z * Wl[(k+2)*HID + c] + xv.w * Wl[(k+3)*HID + c];
        }
        h[r * HID + c] = __float2half(acc * dinv[r]);
    }
}

// ---------------------------------------------------------------- GCN aggregate -> h1 fp16 (relu), fused attention dots
__global__ __launch_bounds__(256) void gcn_agg(const __half* __restrict__ h,
                                               const int* __restrict__ rowptr,
                                               const int* __restrict__ colidx,
                                               const float* __restrict__ dinv,
                                               const float* __restrict__ b,
                                               const float* __restrict__ vsrc,
                                               const float* __restrict__ vdst,
                                               __half* __restrict__ h1,
                                               float* __restrict__ as_o,
                                               float* __restrict__ ad_o) {
    __shared__ int sbuf[4][CHUNK];
    int lane = threadIdx.x & 63, wv = threadIdx.x >> 6;
    int half = lane >> 5, hl = lane & 31;
    int n = blockIdx.x * 4 + wv;
    if (n >= N_NODES) return;
    int rp = rowptr[n], re = rowptr[n + 1];
    float acc0 = 0.f, acc1 = 0.f;
    const __half* hp = h + hl * 2;
    for (int cb = rp; cb < re; cb += CHUNK) {
        int ce = min(cb + CHUNK, re);
        for (int e = cb + lane; e < ce; e += 64) sbuf[wv][e - cb] = colidx[e];
        int m = ce - cb;
        int npair = m >> 1;
#pragma unroll 2
        for (int i = 0; i < npair; i++) {
            int s = sbuf[wv][i * 2 + half];
            float2 hv = __half22float2(*(const __half2*)&hp[s * HID]);
            acc0 += hv.x; acc1 += hv.y;
        }
        if (m & 1) {
            int s = sbuf[wv][m - 1];
            float2 hv = __half22float2(*(const __half2*)&hp[s * HID]);
            if (half == 0) { acc0 += hv.x; acc1 += hv.y; }
        }
    }
    acc0 += __shfl_xor(acc0, 32);
    acc1 += __shfl_xor(acc1, 32);
    float dn = dinv[n];
    float2 bb = *(const float2*)&b[hl * 2];
    float v0 = fmaxf(acc0 * dn + bb.x, 0.f);
    float v1 = fmaxf(acc1 * dn + bb.y, 0.f);
    if (half == 0)
        *(__half2*)&h1[n * HID + hl * 2] = __floats2half2_rn(v0, v1);
    float msk = (half == 0) ? 1.f : 0.f;
#pragma unroll
    for (int hh = 0; hh < 4; hh++) {
        float2 vsp = *(const float2*)&vsrc[hh * 64 + hl * 2];
        float2 vdp = *(const float2*)&vdst[hh * 64 + hl * 2];
        float vs = msk * (v0 * vsp.x + v1 * vsp.y);
        float vd = msk * (v0 * vdp.x + v1 * vdp.y);
#pragma unroll
        for (int off = 16; off > 0; off >>= 1) {
            vs += __shfl_xor(vs, off);
            vd += __shfl_xor(vd, off);
        }
        if (lane == 0) {
            as_o[n * 4 + hh] = vs;
            ad_o[n * 4 + hh] = vd;
        }
    }
}

// ---------------------------------------------------------------- GAT aggregate over fp16 h1 -> u fp32 (pre-divided)
__global__ __launch_bounds__(256) void gat_agg(const __half* __restrict__ h1,
                                               const int* __restrict__ rowptr,
                                               const int* __restrict__ colidx,
                                               const float* __restrict__ a_s,
                                               const float* __restrict__ a_d,
                                               float* __restrict__ u) {
    __shared__ float wbuf[4][(CHUNK + 1) * 4];
    __shared__ int   sbuf[4][CHUNK + 1];
    int lane = threadIdx.x & 63, wv = threadIdx.x >> 6;
    int half = lane >> 5, hl = lane & 31;
    int n = blockIdx.x * 4 + wv;
    if (n >= N_NODES) return;
    int rp = rowptr[n], re = rowptr[n + 1];
    float4 ad4 = *(const float4*)&a_d[n * 4];

    float mx = -1e30f, my = -1e30f, mz = -1e30f, mw = -1e30f;
    for (int e = rp + lane; e < re; e += 64) {
        int s = colidx[e];
        float4 a = *(const float4*)&a_s[s * 4];
        mx = fmaxf(mx, a.x); my = fmaxf(my, a.y);
        mz = fmaxf(mz, a.z); mw = fmaxf(mw, a.w);
    }
#pragma unroll
    for (int off = 32; off > 0; off >>= 1) {
        mx = fmaxf(mx, __shfl_xor(mx, off));
        my = fmaxf(my, __shfl_xor(my, off));
        mz = fmaxf(mz, __shfl_xor(mz, off));
        mw = fmaxf(mw, __shfl_xor(mw, off));
    }
    mx += ad4.x; mx = fmaxf(mx, NEG_SLOPE * mx);
    my += ad4.y; my = fmaxf(my, NEG_SLOPE * my);
    mz += ad4.z; mz = fmaxf(mz, NEG_SLOPE * mz);
    mw += ad4.w; mw = fmaxf(mw, NEG_SLOPE * mw);

    float dnx = 0.f, dny = 0.f, dnz = 0.f, dnw = 0.f;
    float a00 = 0.f, a01 = 0.f, a10 = 0.f, a11 = 0.f;
    float a20 = 0.f, a21 = 0.f, a30 = 0.f, a31 = 0.f;
    const __half* hp = h1 + hl * 2;
    for (int cb = rp; cb < re; cb += CHUNK) {
        int ce = min(cb + CHUNK, re);
        for (int e = cb + lane; e < ce; e += 64) {
            int s = colidx[e];
            float4 a = *(const float4*)&a_s[s * 4];
            float vx = a.x + ad4.x; vx = fmaxf(vx, NEG_SLOPE * vx);
            float vy = a.y + ad4.y; vy = fmaxf(vy, NEG_SLOPE * vy);
            float vz = a.z + ad4.z; vz = fmaxf(vz, NEG_SLOPE * vz);
            float vw = a.w + ad4.w; vw = fmaxf(vw, NEG_SLOPE * vw);
            float wx = __expf(vx - mx), wy = __expf(vy - my);
            float wz = __expf(vz - mz), ww = __expf(vw - mw);
            dnx += wx; dny += wy; dnz += wz; dnw += ww;
            int idx = e - cb;
            *(float4*)&wbuf[wv][idx * 4] = make_float4(wx, wy, wz, ww);
            sbuf[wv][idx] = s;
        }
        int m = ce - cb;
        if ((m & 1) && lane == 0) {
            sbuf[wv][m] = n;
            *(float4*)&wbuf[wv][m * 4] = make_float4(0.f, 0.f, 0.f, 0.f);
        }
        int npair = (m + 1) >> 1;
#pragma unroll 2
        for (int i = 0; i < npair; i++) {
            int idx2 = i * 2 + half;
            int s = sbuf[wv][idx2];
            float4 w4 = *(const float4*)&wbuf[wv][idx2 * 4];
            float2 g = __half22float2(*(const __half2*)&hp[s * HID]);
            a00 += w4.x * g.x; a01 += w4.x * g.y;
            a10 += w4.y * g.x; a11 += w4.y * g.y;
            a20 += w4.z * g.x; a21 += w4.z * g.y;
            a30 += w4.w * g.x; a31 += w4.w * g.y;
        }
    }
    a00 += __shfl_xor(a00, 32); a01 += __shfl_xor(a01, 32);
    a10 += __shfl_xor(a10, 32); a11 += __shfl_xor(a11, 32);
    a20 += __shfl_xor(a20, 32); a21 += __shfl_xor(a21, 32);
    a30 += __shfl_xor(a30, 32); a31 += __shfl_xor(a31, 32);
#pragma unroll
    for (int off = 32; off > 0; off >>= 1) {
        dnx += __shfl_xor(dnx, off);
        dny += __shfl_xor(dny, off);
        dnz += __shfl_xor(dnz, off);
        dnw += __shfl_xor(dnw, off);
    }
    if (half == 0) {
        float* up = u + n * 256 + hl * 2;
        *(float2*)&up[0]   = make_float2(a00 / dnx, a01 / dnx);
        *(float2*)&up[64]  = make_float2(a10 / dny, a11 / dny);
        *(float2*)&up[128] = make_float2(a20 / dnz, a21 / dnz);
        *(float2*)&up[192] = make_float2(a30 / dnw, a31 / dnw);
    }
}

// ---------------------------------------------------------------- gemm2b (MFMA): h2 = relu(u @ blockdiag(W_gat) + b)
__global__ __launch_bounds__(256) void gemm2b(const float* __restrict__ u,
                                              const float* __restrict__ W,
                                              const float* __restrict__ b,
                                              float* __restrict__ h2) {
    int lane = threadIdx.x & 63, hd = threadIdx.x >> 6;
    int quad = lane >> 4, l16 = lane & 15;
    half8 Bf[4][2];
#pragma unroll
    for (int nt = 0; nt < 4; nt++)
#pragma unroll
        for (int kc = 0; kc < 2; kc++) {
            const float* wp = W + (kc * 32 + quad * 8) * 256 + hd * 64 + nt * 16 + l16;
#pragma unroll
            for (int j = 0; j < 8; j++)
                Bf[nt][kc][j] = (_Float16)wp[j * 256];
        }
    float bb[4];
#pragma unroll
    for (int nt = 0; nt < 4; nt++) bb[nt] = b[hd * 64 + nt * 16 + l16];

    int rt0 = blockIdx.x * 5;
#pragma unroll
    for (int i = 0; i < 5; i++) {
        int rt = rt0 + i;
        const float* up = u + ((size_t)(rt * 16 + l16)) * 256 + hd * 64 + quad * 8;
        float4 a0 = *(const float4*)up;
        float4 a1 = *(const float4*)(up + 4);
        float4 a2 = *(const float4*)(up + 32);
        float4 a3 = *(const float4*)(up + 36);
        half8 A0, A1;
        A0[0]=(_Float16)a0.x; A0[1]=(_Float16)a0.y; A0[2]=(_Float16)a0.z; A0[3]=(_Float16)a0.w;
        A0[4]=(_Float16)a1.x; A0[5]=(_Float16)a1.y; A0[6]=(_Float16)a1.z; A0[7]=(_Float16)a1.w;
        A1[0]=(_Float16)a2.x; A1[1]=(_Float16)a2.y; A1[2]=(_Float16)a2.z; A1[3]=(_Float16)a2.w;
        A1[4]=(_Float16)a3.x; A1[5]=(_Float16)a3.y; A1[6]=(_Float16)a3.z; A1[7]=(_Float16)a3.w;
        f32x4 acc[4];
#pragma unroll
        for (int nt = 0; nt < 4; nt++) {
            acc[nt] = (f32x4){0.f, 0.f, 0.f, 0.f};
            acc[nt] = __builtin_amdgcn_mfma_f32_16x16x32_f16(A0, Bf[nt][0], acc[nt], 0, 0, 0);
            acc[nt] = __builtin_amdgcn_mfma_f32_16x16x32_f16(A1, Bf[nt][1], acc[nt], 0, 0, 0);
        }
#pragma unroll
        for (int nt = 0; nt < 4; nt++) {
            int col = hd * 64 + nt * 16 + l16;
#pragma unroll
            for (int reg = 0; reg < 4; reg++) {
                int row = rt * 16 + quad * 4 + reg;
                h2[(size_t)row * 256 + col] = fmaxf(acc[nt][reg] + bb[nt], 0.f);
            }
        }
    }
}

// ---------------------------------------------------------------- gemm3 (MFMA): out = h2 @ W_fc + b_fc
__global__ __launch_bounds__(256) void gemm3(const float* __restrict__ h2,
                                             const float* __restrict__ W,
                                             const float* __restrict__ b,
                                             float* __restrict__ out) {
    int lane = threadIdx.x & 63, wv = threadIdx.x >> 6;
    int quad = lane >> 4, l16 = lane & 15;
    half8 Bf[2][8];
#pragma unroll
    for (int nt = 0; nt < 2; nt++)
#pragma unroll
        for (int kc = 0; kc < 8; kc++) {
            const float* wp = W + (kc * 32 + quad * 8) * 32 + nt * 16 + l16;
#pragma unroll
            for (int j = 0; j < 8; j++)
                Bf[nt][kc][j] = (_Float16)wp[j * 32];
        }
    float bb0 = b[l16], bb1 = b[16 + l16];

    for (int tile = blockIdx.x * 4 + wv; tile < NTILES; tile += gridDim.x * 4) {
        const float* hp = h2 + (size_t)(tile * 16 + l16) * 256 + quad * 8;
        f32x4 acc0 = {0.f, 0.f, 0.f, 0.f};
        f32x4 acc1 = {0.f, 0.f, 0.f, 0.f};
#pragma unroll
        for (int kc = 0; kc < 8; kc++) {
            float4 a0 = *(const float4*)(hp + kc * 32);
            float4 a1 = *(const float4*)(hp + kc * 32 + 4);
            half8 A;
            A[0]=(_Float16)a0.x; A[1]=(_Float16)a0.y; A[2]=(_Float16)a0.z; A[3]=(_Float16)a0.w;
            A[4]=(_Float16)a1.x; A[5]=(_Float16)a1.y; A[6]=(_Float16)a1.z; A[7]=(_Float16)a1.w;
            acc0 = __builtin_amdgcn_mfma_f32_16x16x32_f16(A, Bf[0][kc], acc0, 0, 0, 0);
            acc1 = __builtin_amdgcn_mfma_f32_16x16x32_f16(A, Bf[1][kc], acc1, 0, 0, 0);
        }
#pragma unroll
        for (int reg = 0; reg < 4; reg++) {
            int row = tile * 16 + quad * 4 + reg;
            out[row * 32 + l16]      = acc0[reg] + bb0;
            out[row * 32 + 16 + l16] = acc1[reg] + bb1;
        }
    }
}

// ---------------------------------------------------------------- launch
extern "C" void kernel_launch(void* const* d_in, const int* in_sizes, int n_in,
                              void* d_out, int out_size, void* d_ws, size_t ws_size,
                              hipStream_t stream) {
    const float* x      = (const float*)d_in[0];
    const int*   edge   = (const int*)  d_in[1];
    const float* W_gcn  = (const float*)d_in[2];
    const float* b_gcn  = (const float*)d_in[3];
    const float* W_gat  = (const float*)d_in[4];
    const float* att_s  = (const float*)d_in[5];
    const float* att_d  = (const float*)d_in[6];
    const float* b_gat  = (const float*)d_in[7];
    const float* W_fc   = (const float*)d_in[8];
    const float* b_fc   = (const float*)d_in[9];
    float* out = (float*)d_out;

    char* p = (char*)d_ws;
    auto alloc = [&](size_t bytes) {
        char* q = p;
        p += (bytes + 255) & ~(size_t)255;
        return q;
    };
    __half* h     = (__half*)alloc((size_t)N_NODES * HID * 2);
    __half* h1    = (__half*)alloc((size_t)N_NODES * HID * 2);
    float* u      = (float*)alloc((size_t)N_NODES * 256 * 4);
    float* h2     = (float*)alloc((size_t)N_NODES * 256 * 4);
    float* as_a   = (float*)alloc((size_t)N_NODES * 4 * 4);
    float* ad_a   = (float*)alloc((size_t)N_NODES * 4 * 4);
    float* dinv   = (float*)alloc((size_t)N_NODES * 4);
    int*   cnt8   = (int*)  alloc((size_t)NXCD * N_NODES * 4);
    int*   xbase  = (int*)  alloc((size_t)NXCD * N_NODES * 4);
    int*   rowptr = (int*)  alloc((size_t)(N_NODES + 1) * 4);
    int*   colidx = (int*)  alloc((size_t)(N_EDGES + N_NODES) * 4);
    unsigned short* eoff = (unsigned short*)alloc((size_t)N_EDGES * 2);
    int*   bsum   = (int*)  alloc((size_t)NB * 4);
    int*   boff   = (int*)  alloc((size_t)NB * 4);
    float* vsrc   = (float*)alloc((size_t)HEADS * HID * 4);
    float* vdst   = (float*)alloc((size_t)HEADS * HID * 4);

    // CSR build: XCD-privatized counting, atomic-free fill
    hipMemsetAsync(cnt8, 0, (size_t)NXCD * N_NODES * 4, stream);
    count_k   <<<(N_EDGES + 255) / 256, 256, 0, stream>>>(edge, cnt8, eoff);
    blockred_k<<<NB, 256, 0, stream>>>(cnt8, bsum);
    bscan_k   <<<1, 256, 0, stream>>>(bsum, boff, rowptr);
    scatter_k <<<NB, 256, 0, stream>>>(cnt8, boff, rowptr, dinv, colidx, xbase);
    fill2_k   <<<(N_EDGES + 255) / 256, 256, 0, stream>>>(edge, eoff, xbase, colidx);

    // attention projection vectors
    attvec_k<<<1, 256, 0, stream>>>(W_gat, att_s, att_d, vsrc, vdst);

    // GCN
    gemm1   <<<(N_NODES + 31) / 32, 256, 0, stream>>>(x, W_gcn, dinv, h);
    gcn_agg <<<(N_NODES + 3) / 4, 256, 0, stream>>>(h, rowptr, colidx, dinv, b_gcn,
                                                    vsrc, vdst, h1, as_a, ad_a);

    // GAT
    gat_agg <<<(N_NODES + 3) / 4, 256, 0, stream>>>(h1, rowptr, colidx, as_a, ad_a, u);
    gemm2b  <<<625, 256, 0, stream>>>(u, W_gat, b_gat, h2);

    // FC
    gemm3   <<<256, 256, 0, stream>>>(h2, W_fc, b_fc, out);
}

// Round 8
// 304.752 us; speedup vs baseline: 3.2042x; 1.1055x over previous
//
#include <hip/hip_runtime.h>
#include <hip/hip_bf16.h>
#include <hip/hip_fp16.h>
#include <math.h>

#define N_NODES 50000
#define N_EDGES 1600000
#define D_IN    32
#define HID     64
#define HEADS   4
#define D_OUT   32
#define NEG_SLOPE 0.2f
#define NB 196   // ceil(N_NODES/256)
#define CHUNK 128
#define NTILES 3125   // N_NODES / 16, exact
#define NXCD 8

typedef _Float16 half8 __attribute__((ext_vector_type(8)));
typedef float    f32x4 __attribute__((ext_vector_type(4)));
typedef float    f32x2 __attribute__((ext_vector_type(2)));

// ---------------------------------------------------------------- CSR build (XCD-privatized counters, u16 colidx)
__global__ __launch_bounds__(256) void count_k(const int* __restrict__ edge,
                                               int* __restrict__ cnt8,
                                               unsigned short* __restrict__ eoff) {
    int i = blockIdx.x * 256 + threadIdx.x;
    int x = blockIdx.x & (NXCD - 1);
    if (i < N_EDGES) {
        int d = edge[N_EDGES + i];
        eoff[i] = (unsigned short)atomicAdd(&cnt8[x * N_NODES + d], 1);
    }
}

__global__ __launch_bounds__(256) void blockred_k(const int* __restrict__ cnt8,
                                                  int* __restrict__ bsum) {
    int t = threadIdx.x;
    int i = blockIdx.x * 256 + t;
    int v = 0;
    if (i < N_NODES) {
        v = 1;                            // self-loop
#pragma unroll
        for (int x = 0; x < NXCD; x++) v += cnt8[x * N_NODES + i];
    }
#pragma unroll
    for (int off = 32; off; off >>= 1) v += __shfl_xor(v, off);
    __shared__ int ws[4];
    if ((t & 63) == 0) ws[t >> 6] = v;
    __syncthreads();
    if (t == 0) bsum[blockIdx.x] = ws[0] + ws[1] + ws[2] + ws[3];
}

__global__ __launch_bounds__(256) void bscan_k(const int* __restrict__ bsum,
                                               int* __restrict__ boff,
                                               int* __restrict__ rowptr) {
    int t = threadIdx.x, lane = t & 63, wv = t >> 6;
    int v = (t < NB) ? bsum[t] : 0;
    int inc = v;
#pragma unroll
    for (int d = 1; d < 64; d <<= 1) {
        int u = __shfl_up(inc, d);
        if (lane >= d) inc += u;
    }
    __shared__ int ws[4];
    if (lane == 63) ws[wv] = inc;
    __syncthreads();
    int add = 0;
#pragma unroll
    for (int j = 0; j < 4; j++) if (j < wv) add += ws[j];
    inc += add;
    if (t < NB) boff[t] = inc - v;
    if (t == NB - 1) rowptr[N_NODES] = inc;
}

__global__ __launch_bounds__(256) void scatter_k(const int* __restrict__ cnt8,
                                                 const int* __restrict__ boff,
                                                 int* __restrict__ rowptr,
                                                 float* __restrict__ dinv,
                                                 unsigned short* __restrict__ colidx,
                                                 int* __restrict__ xbase) {
    int t = threadIdx.x, lane = t & 63, wv = t >> 6;
    int i = blockIdx.x * 256 + t;
    int c8[NXCD];
    int deg = 0;
    if (i < N_NODES) {
        deg = 1;
#pragma unroll
        for (int x = 0; x < NXCD; x++) { c8[x] = cnt8[x * N_NODES + i]; deg += c8[x]; }
    }
    int inc = deg;
#pragma unroll
    for (int d = 1; d < 64; d <<= 1) {
        int u = __shfl_up(inc, d);
        if (lane >= d) inc += u;
    }
    __shared__ int ws[4];
    if (lane == 63) ws[wv] = inc;
    __syncthreads();
    int add = 0;
#pragma unroll
    for (int j = 0; j < 4; j++) if (j < wv) add += ws[j];
    int exc = boff[blockIdx.x] + inc + add - deg;
    if (i < N_NODES) {
        rowptr[i] = exc;
        dinv[i]   = rsqrtf((float)deg);
        colidx[exc] = (unsigned short)i;  // self-loop at slot 0
        int run = exc + 1;
#pragma unroll
        for (int x = 0; x < NXCD; x++) { xbase[x * N_NODES + i] = run; run += c8[x]; }
    }
}

__global__ __launch_bounds__(256) void fill2_k(const int* __restrict__ edge,
                                               const unsigned short* __restrict__ eoff,
                                               const int* __restrict__ xbase,
                                               unsigned short* __restrict__ colidx) {
    int i = blockIdx.x * 256 + threadIdx.x;
    int x = blockIdx.x & (NXCD - 1);      // same geometry as count_k -> same label
    if (i < N_EDGES) {
        int s = edge[i], d = edge[N_EDGES + i];
        colidx[xbase[x * N_NODES + d] + (int)eoff[i]] = (unsigned short)s;
    }
}

// ---------------------------------------------------------------- attention projection vectors
__global__ __launch_bounds__(256) void attvec_k(const float* __restrict__ W,
                                                const float* __restrict__ att_s,
                                                const float* __restrict__ att_d,
                                                float* __restrict__ vsrc,
                                                float* __restrict__ vdst) {
    int t = threadIdx.x;
    int h = t >> 6, k = t & 63;
    float s_ = 0.f, d_ = 0.f;
#pragma unroll 8
    for (int c = 0; c < 64; c++) {
        float w = W[k * 256 + h * 64 + c];
        s_ += w * att_s[h * 64 + c];
        d_ += w * att_d[h * 64 + c];
    }
    vsrc[h * 64 + k] = s_;
    vdst[h * 64 + k] = d_;
}

// ---------------------------------------------------------------- GEMM1: h = fp16( dinv .* (x @ W_gcn) )
__global__ __launch_bounds__(256) void gemm1(const float* __restrict__ x,
                                             const float* __restrict__ W,
                                             const float* __restrict__ dinv,
                                             __half* __restrict__ h) {
    __shared__ float Wl[D_IN * HID];      // 8 KB
    int t = threadIdx.x;
    for (int i = t; i < D_IN * HID; i += 256) Wl[i] = W[i];
    __syncthreads();
    int c = t & 63, rw = t >> 6;
    int r0 = blockIdx.x * 32;
#pragma unroll
    for (int rr = 0; rr < 8; rr++) {
        int r = r0 + rr * 4 + rw;
        if (r >= N_NODES) break;
        const float4* xr4 = (const float4*)(x + r * D_IN);
        float acc = 0.f;
#pragma unroll
        for (int k4 = 0; k4 < D_IN / 4; k4++) {
            float4 xv = xr4[k4];
            int k = k4 * 4;
            acc += xv.x * Wl[(k+0)*HID + c] + xv.y * Wl[(k+1)*HID + c]
                 + xv.z * Wl[(k+2)*HID + c] + xv.w * Wl[(k+3)*HID + c];
        }
        h[r * HID + c] = __float2half(acc * dinv[r]);
    }
}

// ---------------------------------------------------------------- GCN aggregate -> h1 fp16 (relu), fused attention dots
// wave = node; 4 edges/iter (quarter-wave each); lane holds 4 channels (8B dwordx2).
__global__ __launch_bounds__(256) void gcn_agg(const __half* __restrict__ h,
                                               const int* __restrict__ rowptr,
                                               const unsigned short* __restrict__ colidx,
                                               const float* __restrict__ dinv,
                                               const float* __restrict__ b,
                                               const float* __restrict__ vsrc,
                                               const float* __restrict__ vdst,
                                               __half* __restrict__ h1,
                                               float* __restrict__ as_o,
                                               float* __restrict__ ad_o) {
    __shared__ int sbuf[4][CHUNK + 4];
    int lane = threadIdx.x & 63, wv = threadIdx.x >> 6;
    int quarter = lane >> 4, ql = lane & 15;
    int n = blockIdx.x * 4 + wv;
    if (n >= N_NODES) return;
    int rp = rowptr[n], re = rowptr[n + 1];
    f32x2 a01 = {0.f, 0.f}, a23 = {0.f, 0.f};
    const __half* hp = h + ql * 4;
    for (int cb = rp; cb < re; cb += CHUNK) {
        int ce = min(cb + CHUNK, re);
        for (int e = cb + lane; e < ce; e += 64) sbuf[wv][e - cb] = colidx[e];
        int m = ce - cb;
        int pad = (4 - (m & 3)) & 3;
        if (lane < pad) sbuf[wv][m + lane] = N_NODES;   // zero row
        int m4 = (m + pad) >> 2;
#pragma unroll 2
        for (int i = 0; i < m4; i++) {
            int s = sbuf[wv][i * 4 + quarter];
            float2 raw = *(const float2*)(hp + s * HID);    // 4 fp16
            __half2 g0 = __builtin_bit_cast(__half2, raw.x);
            __half2 g1 = __builtin_bit_cast(__half2, raw.y);
            float2 f0 = __half22float2(g0), f1 = __half22float2(g1);
            a01.x += f0.x; a01.y += f0.y;
            a23.x += f1.x; a23.y += f1.y;
        }
    }
    // combine quarters (xor 16, 32)
#pragma unroll
    for (int off = 16; off <= 32; off <<= 1) {
        a01.x += __shfl_xor(a01.x, off); a01.y += __shfl_xor(a01.y, off);
        a23.x += __shfl_xor(a23.x, off); a23.y += __shfl_xor(a23.y, off);
    }
    float dn = dinv[n];
    const float4 bb = *(const float4*)&b[ql * 4];
    float v0 = fmaxf(a01.x * dn + bb.x, 0.f);
    float v1 = fmaxf(a01.y * dn + bb.y, 0.f);
    float v2 = fmaxf(a23.x * dn + bb.z, 0.f);
    float v3 = fmaxf(a23.y * dn + bb.w, 0.f);
    if (quarter == 0) {
        __half2* op = (__half2*)&h1[n * HID + ql * 4];
        op[0] = __floats2half2_rn(v0, v1);
        op[1] = __floats2half2_rn(v2, v3);
    }
    // attention dots (lanes 0-15 hold valid sums; xor offsets <16 stay in-group)
#pragma unroll
    for (int hh = 0; hh < 4; hh++) {
        float4 vsp = *(const float4*)&vsrc[hh * 64 + ql * 4];
        float4 vdp = *(const float4*)&vdst[hh * 64 + ql * 4];
        float vs = v0 * vsp.x + v1 * vsp.y + v2 * vsp.z + v3 * vsp.w;
        float vd = v0 * vdp.x + v1 * vdp.y + v2 * vdp.z + v3 * vdp.w;
#pragma unroll
        for (int off = 8; off > 0; off >>= 1) {
            vs += __shfl_xor(vs, off);
            vd += __shfl_xor(vd, off);
        }
        if (lane == 0) {
            as_o[n * 4 + hh] = vs;
            ad_o[n * 4 + hh] = vd;
        }
    }
}

// ---------------------------------------------------------------- GAT aggregate (no max pass: softmax is shift-invariant,
// logits O(+-5), clamp 80 as overflow insurance) -> u fp16 (pre-divided)
__global__ __launch_bounds__(256) void gat_agg(const __half* __restrict__ h1,
                                               const int* __restrict__ rowptr,
                                               const unsigned short* __restrict__ colidx,
                                               const float* __restrict__ a_s,
                                               const float* __restrict__ a_d,
                                               __half* __restrict__ u) {
    __shared__ float wbuf[4][(CHUNK + 4) * 4];
    __shared__ int   sbuf[4][CHUNK + 4];
    int lane = threadIdx.x & 63, wv = threadIdx.x >> 6;
    int quarter = lane >> 4, ql = lane & 15;
    int n = blockIdx.x * 4 + wv;
    if (n >= N_NODES) return;
    int rp = rowptr[n], re = rowptr[n + 1];
    float4 ad4 = *(const float4*)&a_d[n * 4];

    float dnx = 0.f, dny = 0.f, dnz = 0.f, dnw = 0.f;
    f32x2 acc[4][2];
#pragma unroll
    for (int hh = 0; hh < 4; hh++) { acc[hh][0] = (f32x2){0.f,0.f}; acc[hh][1] = (f32x2){0.f,0.f}; }
    const __half* hp = h1 + ql * 4;
    for (int cb = rp; cb < re; cb += CHUNK) {
        int ce = min(cb + CHUNK, re);
        // phase B: distributed weights -> LDS (w = exp(leaky(logit)), no max shift)
        for (int e = cb + lane; e < ce; e += 64) {
            int s = colidx[e];
            float4 a = *(const float4*)&a_s[s * 4];
            float vx = a.x + ad4.x; vx = fmaxf(vx, NEG_SLOPE * vx);
            float vy = a.y + ad4.y; vy = fmaxf(vy, NEG_SLOPE * vy);
            float vz = a.z + ad4.z; vz = fmaxf(vz, NEG_SLOPE * vz);
            float vw = a.w + ad4.w; vw = fmaxf(vw, NEG_SLOPE * vw);
            float wx = __expf(fminf(vx, 80.f)), wy = __expf(fminf(vy, 80.f));
            float wz = __expf(fminf(vz, 80.f)), ww = __expf(fminf(vw, 80.f));
            dnx += wx; dny += wy; dnz += wz; dnw += ww;
            int idx = e - cb;
            *(float4*)&wbuf[wv][idx * 4] = make_float4(wx, wy, wz, ww);
            sbuf[wv][idx] = s;
        }
        int m = ce - cb;
        int pad = (4 - (m & 3)) & 3;
        if (lane < pad) {                  // zero-weight pads, zero row
            sbuf[wv][m + lane] = N_NODES;
            *(float4*)&wbuf[wv][(m + lane) * 4] = make_float4(0.f, 0.f, 0.f, 0.f);
        }
        int m4 = (m + pad) >> 2;
        // phase C: 4 edges/iter, quarter-wave each, dwordx2 h1 loads
#pragma unroll 2
        for (int i = 0; i < m4; i++) {
            int idx = i * 4 + quarter;
            int s = sbuf[wv][idx];
            float4 w4 = *(const float4*)&wbuf[wv][idx * 4];
            float2 raw = *(const float2*)(hp + s * HID);
            __half2 g0 = __builtin_bit_cast(__half2, raw.x);
            __half2 g1 = __builtin_bit_cast(__half2, raw.y);
            float2 t0 = __half22float2(g0), t1 = __half22float2(g1);
            f32x2 f0 = {t0.x, t0.y}, f1 = {t1.x, t1.y};
            f32x2 wx2 = {w4.x, w4.x}, wy2 = {w4.y, w4.y};
            f32x2 wz2 = {w4.z, w4.z}, ww2 = {w4.w, w4.w};
            acc[0][0] += wx2 * f0; acc[0][1] += wx2 * f1;
            acc[1][0] += wy2 * f0; acc[1][1] += wy2 * f1;
            acc[2][0] += wz2 * f0; acc[2][1] += wz2 * f1;
            acc[3][0] += ww2 * f0; acc[3][1] += ww2 * f1;
        }
    }
    // combine quarters
#pragma unroll
    for (int hh = 0; hh < 4; hh++)
#pragma unroll
        for (int c = 0; c < 2; c++) {
            acc[hh][c].x += __shfl_xor(acc[hh][c].x, 16);
            acc[hh][c].y += __shfl_xor(acc[hh][c].y, 16);
            acc[hh][c].x += __shfl_xor(acc[hh][c].x, 32);
            acc[hh][c].y += __shfl_xor(acc[hh][c].y, 32);
        }
    // reduce denominators across all 64 lanes
#pragma unroll
    for (int off = 32; off > 0; off >>= 1) {
        dnx += __shfl_xor(dnx, off);
        dny += __shfl_xor(dny, off);
        dnz += __shfl_xor(dnz, off);
        dnw += __shfl_xor(dnw, off);
    }
    if (quarter == 0) {
        float r4[4] = {1.f / dnx, 1.f / dny, 1.f / dnz, 1.f / dnw};
        __half* up = u + n * 256 + ql * 4;
#pragma unroll
        for (int hh = 0; hh < 4; hh++) {
            __half2* op = (__half2*)&up[hh * 64];
            op[0] = __floats2half2_rn(acc[hh][0].x * r4[hh], acc[hh][0].y * r4[hh]);
            op[1] = __floats2half2_rn(acc[hh][1].x * r4[hh], acc[hh][1].y * r4[hh]);
        }
    }
}

// ---------------------------------------------------------------- gemm2b (MFMA): h2 = fp16 relu(u @ blockdiag(W_gat) + b)
__global__ __launch_bounds__(256) void gemm2b(const __half* __restrict__ u,
                                              const float* __restrict__ W,
                                              const float* __restrict__ b,
                                              __half* __restrict__ h2) {
    int lane = threadIdx.x & 63, hd = threadIdx.x >> 6;
    int quad = lane >> 4, l16 = lane & 15;
    half8 Bf[4][2];
#pragma unroll
    for (int nt = 0; nt < 4; nt++)
#pragma unroll
        for (int kc = 0; kc < 2; kc++) {
            const float* wp = W + (kc * 32 + quad * 8) * 256 + hd * 64 + nt * 16 + l16;
#pragma unroll
            for (int j = 0; j < 8; j++)
                Bf[nt][kc][j] = (_Float16)wp[j * 256];
        }
    float bb[4];
#pragma unroll
    for (int nt = 0; nt < 4; nt++) bb[nt] = b[hd * 64 + nt * 16 + l16];

    int rt0 = blockIdx.x * 5;
#pragma unroll
    for (int i = 0; i < 5; i++) {
        int rt = rt0 + i;
        const __half* up = u + ((size_t)(rt * 16 + l16)) * 256 + hd * 64 + quad * 8;
        half8 A0 = *(const half8*)(const void*)up;
        half8 A1 = *(const half8*)(const void*)(up + 32);
        f32x4 acc[4];
#pragma unroll
        for (int nt = 0; nt < 4; nt++) {
            acc[nt] = (f32x4){0.f, 0.f, 0.f, 0.f};
            acc[nt] = __builtin_amdgcn_mfma_f32_16x16x32_f16(A0, Bf[nt][0], acc[nt], 0, 0, 0);
            acc[nt] = __builtin_amdgcn_mfma_f32_16x16x32_f16(A1, Bf[nt][1], acc[nt], 0, 0, 0);
        }
#pragma unroll
        for (int nt = 0; nt < 4; nt++) {
            int col = hd * 64 + nt * 16 + l16;
#pragma unroll
            for (int reg = 0; reg < 4; reg++) {
                int row = rt * 16 + quad * 4 + reg;
                h2[(size_t)row * 256 + col] = __float2half(fmaxf(acc[nt][reg] + bb[nt], 0.f));
            }
        }
    }
}

// ---------------------------------------------------------------- gemm3 (MFMA): out = h2 @ W_fc + b_fc
__global__ __launch_bounds__(256) void gemm3(const __half* __restrict__ h2,
                                             const float* __restrict__ W,
                                             const float* __restrict__ b,
                                             float* __restrict__ out) {
    int lane = threadIdx.x & 63, wv = threadIdx.x >> 6;
    int quad = lane >> 4, l16 = lane & 15;
    half8 Bf[2][8];
#pragma unroll
    for (int nt = 0; nt < 2; nt++)
#pragma unroll
        for (int kc = 0; kc < 8; kc++) {
            const float* wp = W + (kc * 32 + quad * 8) * 32 + nt * 16 + l16;
#pragma unroll
            for (int j = 0; j < 8; j++)
                Bf[nt][kc][j] = (_Float16)wp[j * 32];
        }
    float bb0 = b[l16], bb1 = b[16 + l16];

    for (int tile = blockIdx.x * 4 + wv; tile < NTILES; tile += gridDim.x * 4) {
        const __half* hp = h2 + (size_t)(tile * 16 + l16) * 256 + quad * 8;
        f32x4 acc0 = {0.f, 0.f, 0.f, 0.f};
        f32x4 acc1 = {0.f, 0.f, 0.f, 0.f};
#pragma unroll
        for (int kc = 0; kc < 8; kc++) {
            half8 A = *(const half8*)(const void*)(hp + kc * 32);
            acc0 = __builtin_amdgcn_mfma_f32_16x16x32_f16(A, Bf[0][kc], acc0, 0, 0, 0);
            acc1 = __builtin_amdgcn_mfma_f32_16x16x32_f16(A, Bf[1][kc], acc1, 0, 0, 0);
        }
#pragma unroll
        for (int reg = 0; reg < 4; reg++) {
            int row = tile * 16 + quad * 4 + reg;
            out[row * 32 + l16]      = acc0[reg] + bb0;
            out[row * 32 + 16 + l16] = acc1[reg] + bb1;
        }
    }
}

// ---------------------------------------------------------------- launch
extern "C" void kernel_launch(void* const* d_in, const int* in_sizes, int n_in,
                              void* d_out, int out_size, void* d_ws, size_t ws_size,
                              hipStream_t stream) {
    const float* x      = (const float*)d_in[0];
    const int*   edge   = (const int*)  d_in[1];
    const float* W_gcn  = (const float*)d_in[2];
    const float* b_gcn  = (const float*)d_in[3];
    const float* W_gat  = (const float*)d_in[4];
    const float* att_s  = (const float*)d_in[5];
    const float* att_d  = (const float*)d_in[6];
    const float* b_gat  = (const float*)d_in[7];
    const float* W_fc   = (const float*)d_in[8];
    const float* b_fc   = (const float*)d_in[9];
    float* out = (float*)d_out;

    char* p = (char*)d_ws;
    auto alloc = [&](size_t bytes) {
        char* q = p;
        p += (bytes + 255) & ~(size_t)255;
        return q;
    };
    __half* h     = (__half*)alloc((size_t)(N_NODES + 1) * HID * 2);   // +1 zero row
    __half* h1    = (__half*)alloc((size_t)(N_NODES + 1) * HID * 2);   // +1 zero row
    __half* u     = (__half*)alloc((size_t)N_NODES * 256 * 2);
    __half* h2    = (__half*)alloc((size_t)N_NODES * 256 * 2);
    float* as_a   = (float*)alloc((size_t)N_NODES * 4 * 4);
    float* ad_a   = (float*)alloc((size_t)N_NODES * 4 * 4);
    float* dinv   = (float*)alloc((size_t)N_NODES * 4);
    int*   cnt8   = (int*)  alloc((size_t)NXCD * N_NODES * 4);
    int*   xbase  = (int*)  alloc((size_t)NXCD * N_NODES * 4);
    int*   rowptr = (int*)  alloc((size_t)(N_NODES + 1) * 4);
    unsigned short* colidx = (unsigned short*)alloc((size_t)(N_EDGES + N_NODES) * 2);
    unsigned short* eoff   = (unsigned short*)alloc((size_t)N_EDGES * 2);
    int*   bsum   = (int*)  alloc((size_t)NB * 4);
    int*   boff   = (int*)  alloc((size_t)NB * 4);
    float* vsrc   = (float*)alloc((size_t)HEADS * HID * 4);
    float* vdst   = (float*)alloc((size_t)HEADS * HID * 4);

    // zero the private counters and the padding rows
    hipMemsetAsync(cnt8, 0, (size_t)NXCD * N_NODES * 4, stream);
    hipMemsetAsync(h  + (size_t)N_NODES * HID, 0, HID * 2, stream);
    hipMemsetAsync(h1 + (size_t)N_NODES * HID, 0, HID * 2, stream);

    // CSR build
    count_k   <<<(N_EDGES + 255) / 256, 256, 0, stream>>>(edge, cnt8, eoff);
    blockred_k<<<NB, 256, 0, stream>>>(cnt8, bsum);
    bscan_k   <<<1, 256, 0, stream>>>(bsum, boff, rowptr);
    scatter_k <<<NB, 256, 0, stream>>>(cnt8, boff, rowptr, dinv, colidx, xbase);
    fill2_k   <<<(N_EDGES + 255) / 256, 256, 0, stream>>>(edge, eoff, xbase, colidx);

    // attention projection vectors
    attvec_k<<<1, 256, 0, stream>>>(W_gat, att_s, att_d, vsrc, vdst);

    // GCN
    gemm1   <<<(N_NODES + 31) / 32, 256, 0, stream>>>(x, W_gcn, dinv, h);
    gcn_agg <<<(N_NODES + 3) / 4, 256, 0, stream>>>(h, rowptr, colidx, dinv, b_gcn,
                                                    vsrc, vdst, h1, as_a, ad_a);

    // GAT
    gat_agg <<<(N_NODES + 3) / 4, 256, 0, stream>>>(h1, rowptr, colidx, as_a, ad_a, u);
    gemm2b  <<<625, 256, 0, stream>>>(u, W_gat, b_gat, h2);

    // FC
    gemm3   <<<256, 256, 0, stream>>>(h2, W_fc, b_fc, out);
}